// Round 6
// baseline (903.473 us; speedup 1.0000x reference)
//
#include <hip/hip_runtime.h>
#include <hip/hip_bf16.h>
#include <stdint.h>

#define NE 8
#define TKK 2
#define DD 2048
#define FF 4096
#define TT 4096      // tokens = 2*2048
#define CONVP 3072   // convert blocks fused with router in prep

typedef __attribute__((ext_vector_type(8))) short bf16x8;
typedef __attribute__((ext_vector_type(4))) float f32x4;

__device__ inline unsigned short f2bf(float f) {
  union { float f; unsigned u; } x; x.f = f;
  unsigned r = x.u + 0x7fffu + ((x.u >> 16) & 1u);
  return (unsigned short)(r >> 16);
}

__device__ inline bf16x8 cvt8(float4 a, float4 b) {
  union { unsigned short h[8]; bf16x8 v; } x;
  x.h[0] = f2bf(a.x); x.h[1] = f2bf(a.y); x.h[2] = f2bf(a.z); x.h[3] = f2bf(a.w);
  x.h[4] = f2bf(b.x); x.h[5] = f2bf(b.y); x.h[6] = f2bf(b.z); x.h[7] = f2bf(b.w);
  return x.v;
}

__device__ __forceinline__ void conv8(const float* __restrict__ src,
                                      unsigned short* __restrict__ dst, long i) {
  float4 a = *(const float4*)(src + i);
  float4 b = *(const float4*)(src + i + 4);
  union { unsigned short h[8]; uint4 v; } o;
  o.h[0] = f2bf(a.x); o.h[1] = f2bf(a.y); o.h[2] = f2bf(a.z); o.h[3] = f2bf(a.w);
  o.h[4] = f2bf(b.x); o.h[5] = f2bf(b.y); o.h[6] = f2bf(b.z); o.h[7] = f2bf(b.w);
  *(uint4*)(dst + i) = o.v;
}

#define GLL16(g, l) __builtin_amdgcn_global_load_lds( \
    (__attribute__((address_space(1))) void*)(void*)(g), \
    (__attribute__((address_space(3))) void*)(l), 16, 0, 0)

#define LDV(p) (*(const bf16x8*)(p))
#define MF(d, a, b) d = __builtin_amdgcn_mfma_f32_16x16x32_bf16(a, b, d, 0, 0, 0)
#define BARPH() do { asm volatile("" ::: "memory"); __builtin_amdgcn_s_barrier(); \
                     __builtin_amdgcn_sched_barrier(0); } while (0)

// ---------------- router body (one wave = one token) ----------------
__device__ __forceinline__ void router_one(
    int t, int lane, const float* __restrict__ h, const float* __restrict__ gw,
    float* __restrict__ logits, unsigned short* __restrict__ hb,
    int* __restrict__ counts, int* __restrict__ tok_idx,
    int* __restrict__ sel_e, int* __restrict__ sel_slot, float* __restrict__ sel_w) {
  const float4* hr = (const float4*)(h + (size_t)t * DD);
  float4 hv[8];
  float acc[NE];
#pragma unroll
  for (int e = 0; e < NE; e++) acc[e] = 0.f;
#pragma unroll
  for (int j = 0; j < 8; j++) hv[j] = hr[j * 64 + lane];
  ushort4* hbr = (ushort4*)(hb + (size_t)t * DD);
#pragma unroll
  for (int j = 0; j < 8; j++) {
    ushort4 o;
    o.x = f2bf(hv[j].x); o.y = f2bf(hv[j].y); o.z = f2bf(hv[j].z); o.w = f2bf(hv[j].w);
    hbr[j * 64 + lane] = o;
  }
#pragma unroll
  for (int e = 0; e < NE; e++) {
    const float4* g = (const float4*)(gw + (size_t)e * DD);
    float a = 0.f;
#pragma unroll
    for (int j = 0; j < 8; j++) {
      float4 gv = g[j * 64 + lane];
      a += hv[j].x * gv.x + hv[j].y * gv.y + hv[j].z * gv.z + hv[j].w * gv.w;
    }
    acc[e] = a;
  }
#pragma unroll
  for (int e = 0; e < NE; e++) {
    float v = acc[e];
#pragma unroll
    for (int o = 32; o > 0; o >>= 1) v += __shfl_xor(v, o, 64);
    acc[e] = v;
  }
  if (lane == 0) {
#pragma unroll
    for (int e = 0; e < NE; e++) logits[(size_t)t * NE + e] = acc[e];
    int e1 = 0; float m1 = acc[0];
#pragma unroll
    for (int e = 1; e < NE; e++) if (acc[e] > m1) { m1 = acc[e]; e1 = e; }
    int e2 = -1; float m2 = -3.4e38f;
#pragma unroll
    for (int e = 0; e < NE; e++) if (e != e1 && acc[e] > m2) { m2 = acc[e]; e2 = e; }
    float s = expf(m2 - m1);
    float wa = 1.f / (1.f + s);
    float wb = s * wa;
    int s1 = atomicAdd(&counts[e1], 1);
    tok_idx[e1 * TT + s1] = t;
    int s2 = atomicAdd(&counts[e2], 1);
    tok_idx[e2 * TT + s2] = t;
    sel_e[2 * t] = e1; sel_slot[2 * t] = s1; sel_w[2 * t] = wa;
    sel_e[2 * t + 1] = e2; sel_slot[2 * t + 1] = s2; sel_w[2 * t + 1] = wb;
  }
}

__global__ void router_kernel(const float* __restrict__ h, const float* __restrict__ gw,
                              float* __restrict__ logits, unsigned short* __restrict__ hb,
                              int* __restrict__ counts, int* __restrict__ tok_idx,
                              int* __restrict__ sel_e, int* __restrict__ sel_slot,
                              float* __restrict__ sel_w) {
  router_one(blockIdx.x, threadIdx.x, h, gw, logits, hb, counts, tok_idx, sel_e, sel_slot, sel_w);
}

// ---------------- prep: w1/w3/w2 convert + router, one dispatch ----------------
__global__ __launch_bounds__(256) void prep_kernel(
    const float* __restrict__ h, const float* __restrict__ gw,
    float* __restrict__ logits, unsigned short* __restrict__ hb,
    int* __restrict__ counts, int* __restrict__ tok_idx,
    int* __restrict__ sel_e, int* __restrict__ sel_slot, float* __restrict__ sel_w,
    const float* __restrict__ w1, unsigned short* __restrict__ w1b,
    const float* __restrict__ w3, unsigned short* __restrict__ w3b,
    const float* __restrict__ w2, unsigned short* __restrict__ w2b) {
  if (blockIdx.x < CONVP) {
    long nw = (long)NE * FF * DD;
    long i = ((long)blockIdx.x * 256 + threadIdx.x) * 8;
    long stride = (long)CONVP * 256 * 8;
    for (; i < 3 * nw; i += stride) {
      if (i < nw)          conv8(w1, w1b, i);
      else if (i < 2 * nw) conv8(w3, w3b, i - nw);
      else                 conv8(w2, w2b, i - 2 * nw);
    }
    return;
  }
  int b = blockIdx.x - CONVP;
  router_one(b * 4 + (threadIdx.x >> 6), threadIdx.x & 63,
             h, gw, logits, hb, counts, tok_idx, sel_e, sel_slot, sel_w);
}

__global__ void offsets_kernel(const int* __restrict__ counts, int* __restrict__ offsets) {
  if (threadIdx.x == 0) {
    int r = 0;
    for (int e = 0; e < NE; e++) { offsets[e] = r; r += counts[e]; }
  }
}

// =========================================================================
// 8-phase pipelined GEMMs. BM=256, BN=128, BK=64, 8 waves (2M x 4N),
// double-buffered LDS, counted vmcnt(2) at phases 0/1, raw barrier per phase.
// Issue order per K-tile (gemm1): A0,A2 | B1_0,B1_1 | B3_0,B3_1 | A1,A3
//   -> after vmcnt(2) at next tile's ph0, incomplete set subset of {A1,A3}
//      (needed only at ph1, whose vmcnt(2) then covers them). FIFO-verified.
// =========================================================================

// ---- gemm1_8p: gated = silu(X w1^T) * (X w3^T), dual-B, K=DD ----
// grid: 4096 = x(8) * m(16) * q(32); p = x+8q -> n = p&31 (F-tile of 128), e = p>>5
__global__ __launch_bounds__(512, 2) void gemm1_8p(
    const unsigned short* __restrict__ w1b, const unsigned short* __restrict__ w3b,
    const unsigned short* __restrict__ hb, const int* __restrict__ tok_idx,
    const int* __restrict__ counts, const int* __restrict__ offsets,
    unsigned short* __restrict__ gated) {
  __shared__ __align__(16) char lds[131072];  // A[2][256][64]b16 @0, B1[2][128][64] @65536, B3 @98304

  int bid = blockIdx.x;
  int x = bid & 7, rest = bid >> 3;
  int m = rest & 15, q = rest >> 4;
  int p = x + 8 * q;
  int n = p & 31, e = p >> 5;
  int cnt = counts[e];
  int row0 = m * 256;
  if (row0 >= cnt) return;
  int offe = offsets[e];
  int tid = threadIdx.x;
  int lane = tid & 63;
  int wv = tid >> 6;
  int wm = wv >> 2, wn = wv & 3;

  int swz = ((tid & 7) ^ ((tid >> 3) & 7)) * 8;   // element offset, pre-swizzled source
  long asrc[4];
#pragma unroll
  for (int i = 0; i < 4; i++) {
    int r = i * 64 + (tid >> 3);
    int rr = row0 + r; if (rr >= cnt) rr = cnt - 1;
    int tok = tok_idx[e * TT + rr];
    asrc[i] = (long)tok * DD + swz;
  }
  int fbase = n * 128;
  long ebw = (long)e * FF * DD;
  long bs[2];
#pragma unroll
  for (int i = 0; i < 2; i++) {
    int r = i * 64 + (tid >> 3);
    bs[i] = ebw + (long)(fbase + r) * DD + swz;
  }

#define G1A(c, i, ko)  GLL16(hb  + asrc[i] + (ko), lds +           (c) * 32768 + (i) * 8192 + tid * 16)
#define G1B1(c, i, ko) GLL16(w1b + bs[i]   + (ko), lds + 65536 +  (c) * 16384 + (i) * 8192 + tid * 16)
#define G1B3(c, i, ko) GLL16(w3b + bs[i]   + (ko), lds + 98304 +  (c) * 16384 + (i) * 8192 + tid * 16)

  int arow[8], brow[2];
#pragma unroll
  for (int i = 0; i < 8; i++) arow[i] = (wm * 128 + i * 16 + (lane & 15)) * 128;
#pragma unroll
  for (int j = 0; j < 2; j++) brow[j] = (wn * 32 + j * 16 + (lane & 15)) * 128;
  int kx0 = (((lane >> 4)) ^ (lane & 7)) * 16;
  int kx1 = ((4 + (lane >> 4)) ^ (lane & 7)) * 16;

  f32x4 acc1[8][2], acc3[8][2];
#pragma unroll
  for (int i = 0; i < 8; i++)
#pragma unroll
    for (int j = 0; j < 2; j++) { acc1[i][j] = (f32x4){0,0,0,0}; acc3[i][j] = (f32x4){0,0,0,0}; }

  // prologue: tile 0 into buf 0, consumer order
  G1A(0, 0, 0); G1A(0, 2, 0);
  G1B1(0, 0, 0); G1B1(0, 1, 0);
  G1B3(0, 0, 0); G1B3(0, 1, 0);
  G1A(0, 1, 0); G1A(0, 3, 0);

  int cur = 0;
  bf16x8 b10, b11, b30, b31;
  for (int kt = 0; kt < DD / 64; kt++) {
    int ko = (kt + 1) * 64;
    bool st = (kt < DD / 64 - 1);
    int nc = cur ^ 1;
    const char* Ac  = lds + cur * 32768;
    const char* B1c = lds + 65536 + cur * 16384;
    const char* B3c = lds + 98304 + cur * 16384;

    // ---- phase 0: kk=0, rows 0..3 ----
    asm volatile("s_waitcnt vmcnt(2)" ::: "memory");
    BARPH();
    if (st) { G1A(nc, 0, ko); G1A(nc, 2, ko); }
    b10 = LDV(B1c + brow[0] + kx0); b11 = LDV(B1c + brow[1] + kx0);
    b30 = LDV(B3c + brow[0] + kx0); b31 = LDV(B3c + brow[1] + kx0);
    __builtin_amdgcn_s_setprio(1);
#pragma unroll
    for (int i = 0; i < 4; i++) {
      bf16x8 av = LDV(Ac + arow[i] + kx0);
      MF(acc1[i][0], av, b10); MF(acc1[i][1], av, b11);
      MF(acc3[i][0], av, b30); MF(acc3[i][1], av, b31);
    }
    __builtin_amdgcn_s_setprio(0);

    // ---- phase 1: kk=0, rows 4..7 ----
    if (st) asm volatile("s_waitcnt vmcnt(2)" ::: "memory");
    else    asm volatile("s_waitcnt vmcnt(0)" ::: "memory");
    BARPH();
    if (st) { G1B1(nc, 0, ko); G1B1(nc, 1, ko); }
    __builtin_amdgcn_s_setprio(1);
#pragma unroll
    for (int i = 4; i < 8; i++) {
      bf16x8 av = LDV(Ac + arow[i] + kx0);
      MF(acc1[i][0], av, b10); MF(acc1[i][1], av, b11);
      MF(acc3[i][0], av, b30); MF(acc3[i][1], av, b31);
    }
    __builtin_amdgcn_s_setprio(0);

    // ---- phase 2: kk=1, rows 0..3 ----
    BARPH();
    if (st) { G1B3(nc, 0, ko); G1B3(nc, 1, ko); }
    b10 = LDV(B1c + brow[0] + kx1); b11 = LDV(B1c + brow[1] + kx1);
    b30 = LDV(B3c + brow[0] + kx1); b31 = LDV(B3c + brow[1] + kx1);
    __builtin_amdgcn_s_setprio(1);
#pragma unroll
    for (int i = 0; i < 4; i++) {
      bf16x8 av = LDV(Ac + arow[i] + kx1);
      MF(acc1[i][0], av, b10); MF(acc1[i][1], av, b11);
      MF(acc3[i][0], av, b30); MF(acc3[i][1], av, b31);
    }
    __builtin_amdgcn_s_setprio(0);

    // ---- phase 3: kk=1, rows 4..7 ----
    BARPH();
    if (st) { G1A(nc, 1, ko); G1A(nc, 3, ko); }
    __builtin_amdgcn_s_setprio(1);
#pragma unroll
    for (int i = 4; i < 8; i++) {
      bf16x8 av = LDV(Ac + arow[i] + kx1);
      MF(acc1[i][0], av, b10); MF(acc1[i][1], av, b11);
      MF(acc3[i][0], av, b30); MF(acc3[i][1], av, b31);
    }
    __builtin_amdgcn_s_setprio(0);
    cur = nc;
  }

  // epilogue: silu(c1)*c3 -> bf16
  int r0 = wm * 128 + ((lane >> 4) << 2);
  int c0 = fbase + wn * 32 + (lane & 15);
#pragma unroll
  for (int i = 0; i < 8; i++)
#pragma unroll
    for (int j = 0; j < 2; j++)
#pragma unroll
      for (int r = 0; r < 4; r++) {
        int tr = r0 + i * 16 + r;
        if (row0 + tr < cnt) {
          float g = acc1[i][j][r];
          float sg = g / (1.f + __expf(-g));
          gated[(size_t)(offe + row0 + tr) * FF + (c0 + j * 16)] = f2bf(sg * acc3[i][j][r]);
        }
      }
}

// ---- gemm2_8p: eout = gated w2^T (fp32 out), single-B, K=FF ----
// grid: 2048 = x(8) * m(16) * q(16); p = x+8q -> n = p&15 (D-tile of 128), e = p>>4
// Issue order per K-tile: A0,A2 | B0,B1 | A1,A3 | -
__global__ __launch_bounds__(512, 2) void gemm2_8p(
    const unsigned short* __restrict__ w2b, const unsigned short* __restrict__ gated,
    const int* __restrict__ counts, const int* __restrict__ offsets,
    float* __restrict__ eout) {
  __shared__ __align__(16) char lds[98304];  // A[2][256][64] @0, B[2][128][64] @65536

  int bid = blockIdx.x;
  int x = bid & 7, rest = bid >> 3;
  int m = rest & 15, q = rest >> 4;
  int p = x + 8 * q;
  int n = p & 15, e = p >> 4;
  int cnt = counts[e];
  int row0 = m * 256;
  if (row0 >= cnt) return;
  int offe = offsets[e];
  int tid = threadIdx.x;
  int lane = tid & 63;
  int wv = tid >> 6;
  int wm = wv >> 2, wn = wv & 3;

  int swz = ((tid & 7) ^ ((tid >> 3) & 7)) * 8;
  long asrc[4];
#pragma unroll
  for (int i = 0; i < 4; i++) {
    int r = i * 64 + (tid >> 3);
    int rr = row0 + r; if (rr >= cnt) rr = cnt - 1;
    asrc[i] = (long)(offe + rr) * FF + swz;
  }
  int dbase = n * 128;
  long ebw = (long)e * DD * FF;
  long bs[2];
#pragma unroll
  for (int i = 0; i < 2; i++) {
    int r = i * 64 + (tid >> 3);
    bs[i] = ebw + (long)(dbase + r) * FF + swz;
  }

#define G2A(c, i, ko) GLL16(gated + asrc[i] + (ko), lds +          (c) * 32768 + (i) * 8192 + tid * 16)
#define G2B(c, i, ko) GLL16(w2b   + bs[i]   + (ko), lds + 65536 + (c) * 16384 + (i) * 8192 + tid * 16)

  int arow[8], brow[2];
#pragma unroll
  for (int i = 0; i < 8; i++) arow[i] = (wm * 128 + i * 16 + (lane & 15)) * 128;
#pragma unroll
  for (int j = 0; j < 2; j++) brow[j] = (wn * 32 + j * 16 + (lane & 15)) * 128;
  int kx0 = (((lane >> 4)) ^ (lane & 7)) * 16;
  int kx1 = ((4 + (lane >> 4)) ^ (lane & 7)) * 16;

  f32x4 acc[8][2];
#pragma unroll
  for (int i = 0; i < 8; i++)
#pragma unroll
    for (int j = 0; j < 2; j++) acc[i][j] = (f32x4){0,0,0,0};

  // prologue: tile 0 into buf 0
  G2A(0, 0, 0); G2A(0, 2, 0);
  G2B(0, 0, 0); G2B(0, 1, 0);
  G2A(0, 1, 0); G2A(0, 3, 0);

  int cur = 0;
  bf16x8 b0, b1;
  for (int kt = 0; kt < FF / 64; kt++) {
    int ko = (kt + 1) * 64;
    bool st = (kt < FF / 64 - 1);
    int nc = cur ^ 1;
    const char* Ac = lds + cur * 32768;
    const char* Bc = lds + 65536 + cur * 16384;

    // phase 0: kk=0, rows 0..3
    asm volatile("s_waitcnt vmcnt(2)" ::: "memory");
    BARPH();
    if (st) { G2A(nc, 0, ko); G2A(nc, 2, ko); }
    b0 = LDV(Bc + brow[0] + kx0); b1 = LDV(Bc + brow[1] + kx0);
    __builtin_amdgcn_s_setprio(1);
#pragma unroll
    for (int i = 0; i < 4; i++) {
      bf16x8 av = LDV(Ac + arow[i] + kx0);
      MF(acc[i][0], av, b0); MF(acc[i][1], av, b1);
    }
    __builtin_amdgcn_s_setprio(0);

    // phase 1: kk=0, rows 4..7
    if (st) asm volatile("s_waitcnt vmcnt(2)" ::: "memory");
    else    asm volatile("s_waitcnt vmcnt(0)" ::: "memory");
    BARPH();
    if (st) { G2B(nc, 0, ko); G2B(nc, 1, ko); }
    __builtin_amdgcn_s_setprio(1);
#pragma unroll
    for (int i = 4; i < 8; i++) {
      bf16x8 av = LDV(Ac + arow[i] + kx0);
      MF(acc[i][0], av, b0); MF(acc[i][1], av, b1);
    }
    __builtin_amdgcn_s_setprio(0);

    // phase 2: kk=1, rows 0..3
    BARPH();
    if (st) { G2A(nc, 1, ko); G2A(nc, 3, ko); }
    b0 = LDV(Bc + brow[0] + kx1); b1 = LDV(Bc + brow[1] + kx1);
    __builtin_amdgcn_s_setprio(1);
#pragma unroll
    for (int i = 0; i < 4; i++) {
      bf16x8 av = LDV(Ac + arow[i] + kx1);
      MF(acc[i][0], av, b0); MF(acc[i][1], av, b1);
    }
    __builtin_amdgcn_s_setprio(0);

    // phase 3: kk=1, rows 4..7
    BARPH();
    __builtin_amdgcn_s_setprio(1);
#pragma unroll
    for (int i = 4; i < 8; i++) {
      bf16x8 av = LDV(Ac + arow[i] + kx1);
      MF(acc[i][0], av, b0); MF(acc[i][1], av, b1);
    }
    __builtin_amdgcn_s_setprio(0);
    cur = nc;
  }

  int r0 = wm * 128 + ((lane >> 4) << 2);
  int c0 = dbase + wn * 32 + (lane & 15);
#pragma unroll
  for (int i = 0; i < 8; i++)
#pragma unroll
    for (int j = 0; j < 2; j++)
#pragma unroll
      for (int r = 0; r < 4; r++) {
        int tr = r0 + i * 16 + r;
        if (row0 + tr < cnt)
          eout[(size_t)(offe + row0 + tr) * DD + (c0 + j * 16)] = acc[i][j][r];
      }
}

// ---------------- fallback kernels (ws too small; round-5 verified) ----------------
__global__ __launch_bounds__(256) void gemm1_kernel_fb(
    const float* __restrict__ w1f, const float* __restrict__ w3f,
    const unsigned short* __restrict__ hb, const int* __restrict__ tok_idx,
    const int* __restrict__ counts, const int* __restrict__ offsets,
    unsigned short* __restrict__ gated) {
  __shared__ __align__(16) char lds[49152];
  char* Ab = lds;
  char* B1 = lds + 16384;
  char* B3 = lds + 32768;

  int bid = blockIdx.x;
  int x = bid & 7;
  int rest = bid >> 3;
  int m = rest & 31;
  int q = rest >> 5;
  int p = x + 8 * q;
  int n = p & 63;
  int e = p >> 6;
  int cnt = counts[e];
  int row0 = m * 128;
  if (row0 >= cnt) return;
  int offe = offsets[e];
  int tid = threadIdx.x;

  long asrc[4];
#pragma unroll
  for (int i = 0; i < 4; i++) {
    int r = i * 32 + (tid >> 3);
    int rr = row0 + r; if (rr >= cnt) rr = cnt - 1;
    int tok = tok_idx[e * TT + rr];
    asrc[i] = (long)tok * DD + (((tid & 7) ^ (r & 7)) * 8);
  }
  int fbase = n * 64;
  long ebase = (long)e * FF * DD;
  long bsrc[4];
#pragma unroll
  for (int i = 0; i < 4; i++) {
    int r = i * 16 + (tid >> 4);
    bsrc[i] = ebase + (long)(fbase + r) * DD + (((tid & 15) ^ (r & 15)) * 4);
  }

  f32x4 acc1[4][2], acc3[4][2];
#pragma unroll
  for (int i = 0; i < 4; i++)
#pragma unroll
    for (int j = 0; j < 2; j++) { acc1[i][j] = (f32x4){0,0,0,0}; acc3[i][j] = (f32x4){0,0,0,0}; }

  int wv = tid >> 6;
  int lane = tid & 63;
  int wr = (wv >> 1) * 64;
  int wc = (wv & 1) * 32;
  int lrow = lane & 15;
  int lk4 = lane >> 4;

  for (int k0 = 0; k0 < DD; k0 += 64) {
    if (k0) __syncthreads();
#pragma unroll
    for (int i = 0; i < 4; i++)
      GLL16(hb + asrc[i] + k0, Ab + i * 4096 + tid * 16);
#pragma unroll
    for (int i = 0; i < 4; i++) {
      GLL16(w1f + bsrc[i] + k0, B1 + i * 4096 + tid * 16);
      GLL16(w3f + bsrc[i] + k0, B3 + i * 4096 + tid * 16);
    }
    __syncthreads();
#pragma unroll
    for (int kk = 0; kk < 2; kk++) {
      int kseg = kk * 4 + lk4;
      int fs = kk * 8 + lk4 * 2;
      bf16x8 af[4], b1f[2], b3f[2];
#pragma unroll
      for (int i = 0; i < 4; i++) {
        int row = wr + i * 16 + lrow;
        af[i] = *(const bf16x8*)(Ab + row * 128 + ((kseg ^ (row & 7)) * 16));
      }
#pragma unroll
      for (int j = 0; j < 2; j++) {
        int row = wc + j * 16 + lrow;
        int rx = row & 15;
        float4 a0 = *(const float4*)(B1 + row * 256 + ((fs ^ rx) * 16));
        float4 a1 = *(const float4*)(B1 + row * 256 + (((fs + 1) ^ rx) * 16));
        b1f[j] = cvt8(a0, a1);
        float4 c0 = *(const float4*)(B3 + row * 256 + ((fs ^ rx) * 16));
        float4 c1 = *(const float4*)(B3 + row * 256 + (((fs + 1) ^ rx) * 16));
        b3f[j] = cvt8(c0, c1);
      }
#pragma unroll
      for (int i = 0; i < 4; i++)
#pragma unroll
        for (int j = 0; j < 2; j++) {
          acc1[i][j] = __builtin_amdgcn_mfma_f32_16x16x32_bf16(af[i], b1f[j], acc1[i][j], 0, 0, 0);
          acc3[i][j] = __builtin_amdgcn_mfma_f32_16x16x32_bf16(af[i], b3f[j], acc3[i][j], 0, 0, 0);
        }
    }
  }
  int crow0 = wr + (lane >> 4) * 4;
  int ccol0 = wc + (lane & 15);
#pragma unroll
  for (int i = 0; i < 4; i++)
#pragma unroll
    for (int j = 0; j < 2; j++)
#pragma unroll
      for (int r = 0; r < 4; r++) {
        int trow = crow0 + i * 16 + r;
        if (row0 + trow < cnt) {
          float g = acc1[i][j][r];
          float sg = g / (1.f + __expf(-g));
          float val = sg * acc3[i][j][r];
          gated[(size_t)(offe + row0 + trow) * FF + (fbase + ccol0 + j * 16)] = f2bf(val);
        }
      }
}

__global__ __launch_bounds__(256) void gemm2_kernel_fb(
    const float* __restrict__ w2f, const unsigned short* __restrict__ gated,
    const int* __restrict__ counts, const int* __restrict__ offsets,
    float* __restrict__ eout) {
  __shared__ __align__(16) char lds[49152];
  char* Ab = lds;
  char* Bb = lds + 16384;

  int bid = blockIdx.x;
  int x = bid & 7;
  int rest = bid >> 3;
  int m = rest & 31;
  int q = rest >> 5;
  int p = x + 8 * q;
  int n = p & 15;
  int e = p >> 4;
  int cnt = counts[e];
  int row0 = m * 128;
  if (row0 >= cnt) return;
  int offe = offsets[e];
  int tid = threadIdx.x;

  long asrc[4];
#pragma unroll
  for (int i = 0; i < 4; i++) {
    int r = i * 32 + (tid >> 3);
    int rr = row0 + r; if (rr >= cnt) rr = cnt - 1;
    asrc[i] = (long)(offe + rr) * FF + (((tid & 7) ^ (r & 7)) * 8);
  }
  int dbase = n * 128;
  long ebase = (long)e * DD * FF;
  long bsrc[8];
#pragma unroll
  for (int i = 0; i < 8; i++) {
    int r = i * 16 + (tid >> 4);
    bsrc[i] = ebase + (long)(dbase + r) * FF + (((tid & 15) ^ (r & 15)) * 4);
  }

  f32x4 acc[4][4];
#pragma unroll
  for (int i = 0; i < 4; i++)
#pragma unroll
    for (int j = 0; j < 4; j++) acc[i][j] = (f32x4){0,0,0,0};

  int wv = tid >> 6;
  int lane = tid & 63;
  int wr = (wv >> 1) * 64;
  int wc = (wv & 1) * 64;
  int lrow = lane & 15;
  int lk4 = lane >> 4;

  for (int k0 = 0; k0 < FF; k0 += 64) {
    if (k0) __syncthreads();
#pragma unroll
    for (int i = 0; i < 4; i++)
      GLL16(gated + asrc[i] + k0, Ab + i * 4096 + tid * 16);
#pragma unroll
    for (int i = 0; i < 8; i++)
      GLL16(w2f + bsrc[i] + k0, Bb + i * 4096 + tid * 16);
    __syncthreads();
#pragma unroll
    for (int kk = 0; kk < 2; kk++) {
      int kseg = kk * 4 + lk4;
      int fs = kk * 8 + lk4 * 2;
      bf16x8 af[4], bf[4];
#pragma unroll
      for (int i = 0; i < 4; i++) {
        int row = wr + i * 16 + lrow;
        af[i] = *(const bf16x8*)(Ab + row * 128 + ((kseg ^ (row & 7)) * 16));
      }
#pragma unroll
      for (int j = 0; j < 4; j++) {
        int row = wc + j * 16 + lrow;
        int rx = row & 15;
        float4 a0 = *(const float4*)(Bb + row * 256 + ((fs ^ rx) * 16));
        float4 a1 = *(const float4*)(Bb + row * 256 + (((fs + 1) ^ rx) * 16));
        bf[j] = cvt8(a0, a1);
      }
#pragma unroll
      for (int i = 0; i < 4; i++)
#pragma unroll
        for (int j = 0; j < 4; j++)
          acc[i][j] = __builtin_amdgcn_mfma_f32_16x16x32_bf16(af[i], bf[j], acc[i][j], 0, 0, 0);
    }
  }
  int crow0 = wr + (lane >> 4) * 4;
  int ccol0 = wc + (lane & 15);
#pragma unroll
  for (int i = 0; i < 4; i++)
#pragma unroll
    for (int j = 0; j < 4; j++)
#pragma unroll
      for (int r = 0; r < 4; r++) {
        int trow = crow0 + i * 16 + r;
        if (row0 + trow < cnt)
          eout[(size_t)(offe + row0 + trow) * DD + (dbase + ccol0 + j * 16)] = acc[i][j][r];
      }
}

// ---------------- gather: final = sum_k w_k * eout[slot_k] ----------------
__global__ void gather_kernel(const float* __restrict__ eout, const int* __restrict__ offsets,
                              const int* __restrict__ sel_e, const int* __restrict__ sel_slot,
                              const float* __restrict__ sel_w, float* __restrict__ out) {
  int idx = blockIdx.x * 256 + threadIdx.x;
  int t = idx >> 9;
  int c = idx & 511;
  int ea = sel_e[2 * t], eb = sel_e[2 * t + 1];
  int sa = offsets[ea] + sel_slot[2 * t];
  int sb = offsets[eb] + sel_slot[2 * t + 1];
  float wa = sel_w[2 * t], wb = sel_w[2 * t + 1];
  float4 va = ((const float4*)(eout + (size_t)sa * DD))[c];
  float4 vb = ((const float4*)(eout + (size_t)sb * DD))[c];
  float4 o;
  o.x = wa * va.x + wb * vb.x;
  o.y = wa * va.y + wb * vb.y;
  o.z = wa * va.z + wb * vb.z;
  o.w = wa * va.w + wb * vb.w;
  ((float4*)(out + (size_t)t * DD))[c] = o;
}

extern "C" void kernel_launch(void* const* d_in, const int* in_sizes, int n_in,
                              void* d_out, int out_size, void* d_ws, size_t ws_size,
                              hipStream_t stream) {
  const float* h  = (const float*)d_in[0];
  const float* gw = (const float*)d_in[1];
  const float* w1 = (const float*)d_in[2];
  const float* w2 = (const float*)d_in[3];
  const float* w3 = (const float*)d_in[4];
  float* out = (float*)d_out;
  float* logits = out + (size_t)TT * DD;

  char* wp = (char*)d_ws;
  int* counts = (int*)wp; wp += 256;
  int* offsets = (int*)wp; wp += 256;
  int* tok_idx = (int*)wp; wp += (size_t)NE * TT * 4;
  int* sel_e = (int*)wp; wp += (size_t)TT * 2 * 4;
  int* sel_slot = (int*)wp; wp += (size_t)TT * 2 * 4;
  float* sel_w = (float*)wp; wp += (size_t)TT * 2 * 4;
  unsigned short* hb = (unsigned short*)wp; wp += (size_t)TT * DD * 2;
  unsigned short* gated = (unsigned short*)wp; wp += (size_t)TT * TKK * FF * 2;
  float* eout = (float*)wp; wp += (size_t)TT * TKK * DD * 4;
  if ((size_t)(wp - (char*)d_ws) > ws_size) return;  // base scratch must fit

  long nw = (long)NE * FF * DD;
  unsigned short* w1b = (unsigned short*)wp; wp += (size_t)nw * 2;
  unsigned short* w3b = (unsigned short*)wp; wp += (size_t)nw * 2;
  unsigned short* w2b = (unsigned short*)wp; wp += (size_t)nw * 2;
  bool wb16 = ((size_t)(wp - (char*)d_ws) <= ws_size);

  hipMemsetAsync(counts, 0, 32, stream);
  if (wb16) {
    prep_kernel<<<CONVP + TT / 4, 256, 0, stream>>>(
        h, gw, logits, hb, counts, tok_idx, sel_e, sel_slot, sel_w,
        w1, w1b, w3, w3b, w2, w2b);
    offsets_kernel<<<1, 64, 0, stream>>>(counts, offsets);
    gemm1_8p<<<8 * 16 * 32, 512, 0, stream>>>(w1b, w3b, hb, tok_idx, counts, offsets, gated);
    gemm2_8p<<<8 * 16 * 16, 512, 0, stream>>>(w2b, gated, counts, offsets, eout);
  } else {
    router_kernel<<<TT, 64, 0, stream>>>(h, gw, logits, hb, counts, tok_idx, sel_e, sel_slot, sel_w);
    offsets_kernel<<<1, 64, 0, stream>>>(counts, offsets);
    gemm1_kernel_fb<<<8 * 32 * 64, 256, 0, stream>>>(w1, w3, hb, tok_idx, counts, offsets, gated);
    gemm2_kernel_fb<<<8 * 32 * 16, 256, 0, stream>>>(w2, gated, counts, offsets, eout);
  }
  gather_kernel<<<(TT * DD / 4) / 256, 256, 0, stream>>>(eout, offsets, sel_e, sel_slot, sel_w, out);
}

// Round 7
// 861.440 us; speedup vs baseline: 1.0488x; 1.0488x over previous
//
#include <hip/hip_runtime.h>
#include <hip/hip_bf16.h>
#include <stdint.h>

#define NE 8
#define TKK 2
#define DD 2048
#define FF 4096
#define TT 4096      // tokens = 2*2048
#define NCB 49152    // one-shot convert blocks: 3 * nw / (256*16)

typedef __attribute__((ext_vector_type(8))) short bf16x8;
typedef __attribute__((ext_vector_type(4))) float f32x4;

__device__ inline unsigned short f2bf(float f) {
  union { float f; unsigned u; } x; x.f = f;
  unsigned r = x.u + 0x7fffu + ((x.u >> 16) & 1u);
  return (unsigned short)(r >> 16);
}

__device__ inline bf16x8 cvt8(float4 a, float4 b) {
  union { unsigned short h[8]; bf16x8 v; } x;
  x.h[0] = f2bf(a.x); x.h[1] = f2bf(a.y); x.h[2] = f2bf(a.z); x.h[3] = f2bf(a.w);
  x.h[4] = f2bf(b.x); x.h[5] = f2bf(b.y); x.h[6] = f2bf(b.z); x.h[7] = f2bf(b.w);
  return x.v;
}

// one-shot 16-element convert: 4 independent loads first (ILP), then 2 stores
__device__ __forceinline__ void conv16(const float* __restrict__ src,
                                       unsigned short* __restrict__ dst, long i) {
  float4 a0 = *(const float4*)(src + i);
  float4 a1 = *(const float4*)(src + i + 4);
  float4 a2 = *(const float4*)(src + i + 8);
  float4 a3 = *(const float4*)(src + i + 12);
  union { unsigned short h[8]; uint4 v; } o0, o1;
  o0.h[0] = f2bf(a0.x); o0.h[1] = f2bf(a0.y); o0.h[2] = f2bf(a0.z); o0.h[3] = f2bf(a0.w);
  o0.h[4] = f2bf(a1.x); o0.h[5] = f2bf(a1.y); o0.h[6] = f2bf(a1.z); o0.h[7] = f2bf(a1.w);
  o1.h[0] = f2bf(a2.x); o1.h[1] = f2bf(a2.y); o1.h[2] = f2bf(a2.z); o1.h[3] = f2bf(a2.w);
  o1.h[4] = f2bf(a3.x); o1.h[5] = f2bf(a3.y); o1.h[6] = f2bf(a3.z); o1.h[7] = f2bf(a3.w);
  *(uint4*)(dst + i) = o0.v;
  *(uint4*)(dst + i + 8) = o1.v;
}

__device__ inline void conv8(const float* __restrict__ src,
                             unsigned short* __restrict__ dst, long i) {
  float4 a = *(const float4*)(src + i);
  float4 b = *(const float4*)(src + i + 4);
  union { unsigned short h[8]; uint4 v; } o;
  o.h[0] = f2bf(a.x); o.h[1] = f2bf(a.y); o.h[2] = f2bf(a.z); o.h[3] = f2bf(a.w);
  o.h[4] = f2bf(b.x); o.h[5] = f2bf(b.y); o.h[6] = f2bf(b.z); o.h[7] = f2bf(b.w);
  *(uint4*)(dst + i) = o.v;
}

#define GLL16(g, l) __builtin_amdgcn_global_load_lds( \
    (__attribute__((address_space(1))) void*)(void*)(g), \
    (__attribute__((address_space(3))) void*)(l), 16, 0, 0)

#define LDV(p) (*(const bf16x8*)(p))
#define MF(d, a, b) d = __builtin_amdgcn_mfma_f32_16x16x32_bf16(a, b, d, 0, 0, 0)
#define BARPH() do { asm volatile("" ::: "memory"); __builtin_amdgcn_s_barrier(); \
                     __builtin_amdgcn_sched_barrier(0); } while (0)

// ---------------- router body (one wave = one token) ----------------
__device__ __forceinline__ void router_one(
    int t, int lane, const float* __restrict__ h, const float* __restrict__ gw,
    float* __restrict__ logits, unsigned short* __restrict__ hb,
    int* __restrict__ counts, int* __restrict__ tok_idx,
    int* __restrict__ sel_e, int* __restrict__ sel_slot, float* __restrict__ sel_w) {
  const float4* hr = (const float4*)(h + (size_t)t * DD);
  float4 hv[8];
  float acc[NE];
#pragma unroll
  for (int e = 0; e < NE; e++) acc[e] = 0.f;
#pragma unroll
  for (int j = 0; j < 8; j++) hv[j] = hr[j * 64 + lane];
  ushort4* hbr = (ushort4*)(hb + (size_t)t * DD);
#pragma unroll
  for (int j = 0; j < 8; j++) {
    ushort4 o;
    o.x = f2bf(hv[j].x); o.y = f2bf(hv[j].y); o.z = f2bf(hv[j].z); o.w = f2bf(hv[j].w);
    hbr[j * 64 + lane] = o;
  }
#pragma unroll
  for (int e = 0; e < NE; e++) {
    const float4* g = (const float4*)(gw + (size_t)e * DD);
    float a = 0.f;
#pragma unroll
    for (int j = 0; j < 8; j++) {
      float4 gv = g[j * 64 + lane];
      a += hv[j].x * gv.x + hv[j].y * gv.y + hv[j].z * gv.z + hv[j].w * gv.w;
    }
    acc[e] = a;
  }
#pragma unroll
  for (int e = 0; e < NE; e++) {
    float v = acc[e];
#pragma unroll
    for (int o = 32; o > 0; o >>= 1) v += __shfl_xor(v, o, 64);
    acc[e] = v;
  }
  if (lane == 0) {
#pragma unroll
    for (int e = 0; e < NE; e++) logits[(size_t)t * NE + e] = acc[e];
    int e1 = 0; float m1 = acc[0];
#pragma unroll
    for (int e = 1; e < NE; e++) if (acc[e] > m1) { m1 = acc[e]; e1 = e; }
    int e2 = -1; float m2 = -3.4e38f;
#pragma unroll
    for (int e = 0; e < NE; e++) if (e != e1 && acc[e] > m2) { m2 = acc[e]; e2 = e; }
    float s = expf(m2 - m1);
    float wa = 1.f / (1.f + s);
    float wb = s * wa;
    int s1 = atomicAdd(&counts[e1], 1);
    tok_idx[e1 * TT + s1] = t;
    int s2 = atomicAdd(&counts[e2], 1);
    tok_idx[e2 * TT + s2] = t;
    sel_e[2 * t] = e1; sel_slot[2 * t] = s1; sel_w[2 * t] = wa;
    sel_e[2 * t + 1] = e2; sel_slot[2 * t + 1] = s2; sel_w[2 * t + 1] = wb;
  }
}

__global__ void router_kernel(const float* __restrict__ h, const float* __restrict__ gw,
                              float* __restrict__ logits, unsigned short* __restrict__ hb,
                              int* __restrict__ counts, int* __restrict__ tok_idx,
                              int* __restrict__ sel_e, int* __restrict__ sel_slot,
                              float* __restrict__ sel_w) {
  router_one(blockIdx.x, threadIdx.x, h, gw, logits, hb, counts, tok_idx, sel_e, sel_slot, sel_w);
}

// ---------------- prep: one-shot w1/w3/w2 convert + router, one dispatch ----------------
// Convert blocks: no loop — each thread converts exactly 16 elems (4 indep loads).
__global__ __launch_bounds__(256) void prep_kernel(
    const float* __restrict__ h, const float* __restrict__ gw,
    float* __restrict__ logits, unsigned short* __restrict__ hb,
    int* __restrict__ counts, int* __restrict__ tok_idx,
    int* __restrict__ sel_e, int* __restrict__ sel_slot, float* __restrict__ sel_w,
    const float* __restrict__ w1, unsigned short* __restrict__ w1b,
    const float* __restrict__ w3, unsigned short* __restrict__ w3b,
    const float* __restrict__ w2, unsigned short* __restrict__ w2b) {
  int b = blockIdx.x;
  if (b < NCB) {
    int t = b >> 14;                 // 16384 blocks per tensor
    long j = ((long)(b & 16383) * 256 + threadIdx.x) * 16;
    const float* src = (t == 0) ? w1 : (t == 1) ? w3 : w2;
    unsigned short* dst = (t == 0) ? w1b : (t == 1) ? w3b : w2b;
    conv16(src, dst, j);
    return;
  }
  int rb = b - NCB;
  router_one(rb * 4 + (threadIdx.x >> 6), threadIdx.x & 63,
             h, gw, logits, hb, counts, tok_idx, sel_e, sel_slot, sel_w);
}

__global__ void offsets_kernel(const int* __restrict__ counts, int* __restrict__ offsets) {
  if (threadIdx.x == 0) {
    int r = 0;
    for (int e = 0; e < NE; e++) { offsets[e] = r; r += counts[e]; }
  }
}

// =========================================================================
// 8-phase pipelined GEMMs. BM=256, BN=128, BK=64, 8 waves (2M x 4N),
// double-buffered LDS, counted vmcnt(2) at phases 0/1, raw barrier per phase.
// =========================================================================

// ---- gemm1_8p: gated = silu(X w1^T) * (X w3^T), dual-B, K=DD ----
// grid: 4096 = x(8) * m(16) * q(32); p = x+8q -> n = p&31 (F-tile of 128), e = p>>5
__global__ __launch_bounds__(512, 2) void gemm1_8p(
    const unsigned short* __restrict__ w1b, const unsigned short* __restrict__ w3b,
    const unsigned short* __restrict__ hb, const int* __restrict__ tok_idx,
    const int* __restrict__ counts, const int* __restrict__ offsets,
    unsigned short* __restrict__ gated) {
  __shared__ __align__(16) char lds[131072];  // A[2][256][64]b16 @0, B1[2][128][64] @65536, B3 @98304

  int bid = blockIdx.x;
  int x = bid & 7, rest = bid >> 3;
  int m = rest & 15, q = rest >> 4;
  int p = x + 8 * q;
  int n = p & 31, e = p >> 5;
  int cnt = counts[e];
  int row0 = m * 256;
  if (row0 >= cnt) return;
  int offe = offsets[e];
  int tid = threadIdx.x;
  int lane = tid & 63;
  int wv = tid >> 6;
  int wm = wv >> 2, wn = wv & 3;

  int swz = ((tid & 7) ^ ((tid >> 3) & 7)) * 8;   // element offset, pre-swizzled source
  long asrc[4];
#pragma unroll
  for (int i = 0; i < 4; i++) {
    int r = i * 64 + (tid >> 3);
    int rr = row0 + r; if (rr >= cnt) rr = cnt - 1;
    int tok = tok_idx[e * TT + rr];
    asrc[i] = (long)tok * DD + swz;
  }
  int fbase = n * 128;
  long ebw = (long)e * FF * DD;
  long bs[2];
#pragma unroll
  for (int i = 0; i < 2; i++) {
    int r = i * 64 + (tid >> 3);
    bs[i] = ebw + (long)(fbase + r) * DD + swz;
  }

#define G1A(c, i, ko)  GLL16(hb  + asrc[i] + (ko), lds +           (c) * 32768 + (i) * 8192 + tid * 16)
#define G1B1(c, i, ko) GLL16(w1b + bs[i]   + (ko), lds + 65536 +  (c) * 16384 + (i) * 8192 + tid * 16)
#define G1B3(c, i, ko) GLL16(w3b + bs[i]   + (ko), lds + 98304 +  (c) * 16384 + (i) * 8192 + tid * 16)

  int arow[8], brow[2];
#pragma unroll
  for (int i = 0; i < 8; i++) arow[i] = (wm * 128 + i * 16 + (lane & 15)) * 128;
#pragma unroll
  for (int j = 0; j < 2; j++) brow[j] = (wn * 32 + j * 16 + (lane & 15)) * 128;
  int kx0 = (((lane >> 4)) ^ (lane & 7)) * 16;
  int kx1 = ((4 + (lane >> 4)) ^ (lane & 7)) * 16;

  f32x4 acc1[8][2], acc3[8][2];
#pragma unroll
  for (int i = 0; i < 8; i++)
#pragma unroll
    for (int j = 0; j < 2; j++) { acc1[i][j] = (f32x4){0,0,0,0}; acc3[i][j] = (f32x4){0,0,0,0}; }

  // prologue: tile 0 into buf 0, consumer order
  G1A(0, 0, 0); G1A(0, 2, 0);
  G1B1(0, 0, 0); G1B1(0, 1, 0);
  G1B3(0, 0, 0); G1B3(0, 1, 0);
  G1A(0, 1, 0); G1A(0, 3, 0);

  int cur = 0;
  bf16x8 b10, b11, b30, b31;
  for (int kt = 0; kt < DD / 64; kt++) {
    int ko = (kt + 1) * 64;
    bool st = (kt < DD / 64 - 1);
    int nc = cur ^ 1;
    const char* Ac  = lds + cur * 32768;
    const char* B1c = lds + 65536 + cur * 16384;
    const char* B3c = lds + 98304 + cur * 16384;

    // ---- phase 0: kk=0, rows 0..3 ----
    asm volatile("s_waitcnt vmcnt(2)" ::: "memory");
    BARPH();
    if (st) { G1A(nc, 0, ko); G1A(nc, 2, ko); }
    b10 = LDV(B1c + brow[0] + kx0); b11 = LDV(B1c + brow[1] + kx0);
    b30 = LDV(B3c + brow[0] + kx0); b31 = LDV(B3c + brow[1] + kx0);
    __builtin_amdgcn_s_setprio(1);
#pragma unroll
    for (int i = 0; i < 4; i++) {
      bf16x8 av = LDV(Ac + arow[i] + kx0);
      MF(acc1[i][0], av, b10); MF(acc1[i][1], av, b11);
      MF(acc3[i][0], av, b30); MF(acc3[i][1], av, b31);
    }
    __builtin_amdgcn_s_setprio(0);

    // ---- phase 1: kk=0, rows 4..7 ----
    if (st) asm volatile("s_waitcnt vmcnt(2)" ::: "memory");
    else    asm volatile("s_waitcnt vmcnt(0)" ::: "memory");
    BARPH();
    if (st) { G1B1(nc, 0, ko); G1B1(nc, 1, ko); }
    __builtin_amdgcn_s_setprio(1);
#pragma unroll
    for (int i = 4; i < 8; i++) {
      bf16x8 av = LDV(Ac + arow[i] + kx0);
      MF(acc1[i][0], av, b10); MF(acc1[i][1], av, b11);
      MF(acc3[i][0], av, b30); MF(acc3[i][1], av, b31);
    }
    __builtin_amdgcn_s_setprio(0);

    // ---- phase 2: kk=1, rows 0..3 ----
    BARPH();
    if (st) { G1B3(nc, 0, ko); G1B3(nc, 1, ko); }
    b10 = LDV(B1c + brow[0] + kx1); b11 = LDV(B1c + brow[1] + kx1);
    b30 = LDV(B3c + brow[0] + kx1); b31 = LDV(B3c + brow[1] + kx1);
    __builtin_amdgcn_s_setprio(1);
#pragma unroll
    for (int i = 0; i < 4; i++) {
      bf16x8 av = LDV(Ac + arow[i] + kx1);
      MF(acc1[i][0], av, b10); MF(acc1[i][1], av, b11);
      MF(acc3[i][0], av, b30); MF(acc3[i][1], av, b31);
    }
    __builtin_amdgcn_s_setprio(0);

    // ---- phase 3: kk=1, rows 4..7 ----
    BARPH();
    if (st) { G1A(nc, 1, ko); G1A(nc, 3, ko); }
    __builtin_amdgcn_s_setprio(1);
#pragma unroll
    for (int i = 4; i < 8; i++) {
      bf16x8 av = LDV(Ac + arow[i] + kx1);
      MF(acc1[i][0], av, b10); MF(acc1[i][1], av, b11);
      MF(acc3[i][0], av, b30); MF(acc3[i][1], av, b31);
    }
    __builtin_amdgcn_s_setprio(0);
    cur = nc;
  }

  // epilogue: silu(c1)*c3 -> bf16
  int r0 = wm * 128 + ((lane >> 4) << 2);
  int c0 = fbase + wn * 32 + (lane & 15);
#pragma unroll
  for (int i = 0; i < 8; i++)
#pragma unroll
    for (int j = 0; j < 2; j++)
#pragma unroll
      for (int r = 0; r < 4; r++) {
        int tr = r0 + i * 16 + r;
        if (row0 + tr < cnt) {
          float g = acc1[i][j][r];
          float sg = g / (1.f + __expf(-g));
          gated[(size_t)(offe + row0 + tr) * FF + (c0 + j * 16)] = f2bf(sg * acc3[i][j][r]);
        }
      }
}

// ---- gemm2_8p: eout = gated w2^T (fp32 out), single-B, K=FF ----
// grid: 2048 = x(8) * m(16) * q(16); p = x+8q -> n = p&15 (D-tile of 128), e = p>>4
__global__ __launch_bounds__(512, 2) void gemm2_8p(
    const unsigned short* __restrict__ w2b, const unsigned short* __restrict__ gated,
    const int* __restrict__ counts, const int* __restrict__ offsets,
    float* __restrict__ eout) {
  __shared__ __align__(16) char lds[98304];  // A[2][256][64] @0, B[2][128][64] @65536

  int bid = blockIdx.x;
  int x = bid & 7, rest = bid >> 3;
  int m = rest & 15, q = rest >> 4;
  int p = x + 8 * q;
  int n = p & 15, e = p >> 4;
  int cnt = counts[e];
  int row0 = m * 256;
  if (row0 >= cnt) return;
  int offe = offsets[e];
  int tid = threadIdx.x;
  int lane = tid & 63;
  int wv = tid >> 6;
  int wm = wv >> 2, wn = wv & 3;

  int swz = ((tid & 7) ^ ((tid >> 3) & 7)) * 8;
  long asrc[4];
#pragma unroll
  for (int i = 0; i < 4; i++) {
    int r = i * 64 + (tid >> 3);
    int rr = row0 + r; if (rr >= cnt) rr = cnt - 1;
    asrc[i] = (long)(offe + rr) * FF + swz;
  }
  int dbase = n * 128;
  long ebw = (long)e * DD * FF;
  long bs[2];
#pragma unroll
  for (int i = 0; i < 2; i++) {
    int r = i * 64 + (tid >> 3);
    bs[i] = ebw + (long)(dbase + r) * FF + swz;
  }

#define G2A(c, i, ko) GLL16(gated + asrc[i] + (ko), lds +          (c) * 32768 + (i) * 8192 + tid * 16)
#define G2B(c, i, ko) GLL16(w2b   + bs[i]   + (ko), lds + 65536 + (c) * 16384 + (i) * 8192 + tid * 16)

  int arow[8], brow[2];
#pragma unroll
  for (int i = 0; i < 8; i++) arow[i] = (wm * 128 + i * 16 + (lane & 15)) * 128;
#pragma unroll
  for (int j = 0; j < 2; j++) brow[j] = (wn * 32 + j * 16 + (lane & 15)) * 128;
  int kx0 = (((lane >> 4)) ^ (lane & 7)) * 16;
  int kx1 = ((4 + (lane >> 4)) ^ (lane & 7)) * 16;

  f32x4 acc[8][2];
#pragma unroll
  for (int i = 0; i < 8; i++)
#pragma unroll
    for (int j = 0; j < 2; j++) acc[i][j] = (f32x4){0,0,0,0};

  // prologue: tile 0 into buf 0
  G2A(0, 0, 0); G2A(0, 2, 0);
  G2B(0, 0, 0); G2B(0, 1, 0);
  G2A(0, 1, 0); G2A(0, 3, 0);

  int cur = 0;
  bf16x8 b0, b1;
  for (int kt = 0; kt < FF / 64; kt++) {
    int ko = (kt + 1) * 64;
    bool st = (kt < FF / 64 - 1);
    int nc = cur ^ 1;
    const char* Ac = lds + cur * 32768;
    const char* Bc = lds + 65536 + cur * 16384;

    // phase 0: kk=0, rows 0..3
    asm volatile("s_waitcnt vmcnt(2)" ::: "memory");
    BARPH();
    if (st) { G2A(nc, 0, ko); G2A(nc, 2, ko); }
    b0 = LDV(Bc + brow[0] + kx0); b1 = LDV(Bc + brow[1] + kx0);
    __builtin_amdgcn_s_setprio(1);
#pragma unroll
    for (int i = 0; i < 4; i++) {
      bf16x8 av = LDV(Ac + arow[i] + kx0);
      MF(acc[i][0], av, b0); MF(acc[i][1], av, b1);
    }
    __builtin_amdgcn_s_setprio(0);

    // phase 1: kk=0, rows 4..7
    if (st) asm volatile("s_waitcnt vmcnt(2)" ::: "memory");
    else    asm volatile("s_waitcnt vmcnt(0)" ::: "memory");
    BARPH();
    if (st) { G2B(nc, 0, ko); G2B(nc, 1, ko); }
    __builtin_amdgcn_s_setprio(1);
#pragma unroll
    for (int i = 4; i < 8; i++) {
      bf16x8 av = LDV(Ac + arow[i] + kx0);
      MF(acc[i][0], av, b0); MF(acc[i][1], av, b1);
    }
    __builtin_amdgcn_s_setprio(0);

    // phase 2: kk=1, rows 0..3
    BARPH();
    if (st) { G2A(nc, 1, ko); G2A(nc, 3, ko); }
    b0 = LDV(Bc + brow[0] + kx1); b1 = LDV(Bc + brow[1] + kx1);
    __builtin_amdgcn_s_setprio(1);
#pragma unroll
    for (int i = 0; i < 4; i++) {
      bf16x8 av = LDV(Ac + arow[i] + kx1);
      MF(acc[i][0], av, b0); MF(acc[i][1], av, b1);
    }
    __builtin_amdgcn_s_setprio(0);

    // phase 3: kk=1, rows 4..7
    BARPH();
    __builtin_amdgcn_s_setprio(1);
#pragma unroll
    for (int i = 4; i < 8; i++) {
      bf16x8 av = LDV(Ac + arow[i] + kx1);
      MF(acc[i][0], av, b0); MF(acc[i][1], av, b1);
    }
    __builtin_amdgcn_s_setprio(0);
    cur = nc;
  }

  int r0 = wm * 128 + ((lane >> 4) << 2);
  int c0 = dbase + wn * 32 + (lane & 15);
#pragma unroll
  for (int i = 0; i < 8; i++)
#pragma unroll
    for (int j = 0; j < 2; j++)
#pragma unroll
      for (int r = 0; r < 4; r++) {
        int tr = r0 + i * 16 + r;
        if (row0 + tr < cnt)
          eout[(size_t)(offe + row0 + tr) * DD + (c0 + j * 16)] = acc[i][j][r];
      }
}

// ---------------- fallback kernels (ws too small; round-5 verified) ----------------
__global__ __launch_bounds__(256) void gemm1_kernel_fb(
    const float* __restrict__ w1f, const float* __restrict__ w3f,
    const unsigned short* __restrict__ hb, const int* __restrict__ tok_idx,
    const int* __restrict__ counts, const int* __restrict__ offsets,
    unsigned short* __restrict__ gated) {
  __shared__ __align__(16) char lds[49152];
  char* Ab = lds;
  char* B1 = lds + 16384;
  char* B3 = lds + 32768;

  int bid = blockIdx.x;
  int x = bid & 7;
  int rest = bid >> 3;
  int m = rest & 31;
  int q = rest >> 5;
  int p = x + 8 * q;
  int n = p & 63;
  int e = p >> 6;
  int cnt = counts[e];
  int row0 = m * 128;
  if (row0 >= cnt) return;
  int offe = offsets[e];
  int tid = threadIdx.x;

  long asrc[4];
#pragma unroll
  for (int i = 0; i < 4; i++) {
    int r = i * 32 + (tid >> 3);
    int rr = row0 + r; if (rr >= cnt) rr = cnt - 1;
    int tok = tok_idx[e * TT + rr];
    asrc[i] = (long)tok * DD + (((tid & 7) ^ (r & 7)) * 8);
  }
  int fbase = n * 64;
  long ebase = (long)e * FF * DD;
  long bsrc[4];
#pragma unroll
  for (int i = 0; i < 4; i++) {
    int r = i * 16 + (tid >> 4);
    bsrc[i] = ebase + (long)(fbase + r) * DD + (((tid & 15) ^ (r & 15)) * 4);
  }

  f32x4 acc1[4][2], acc3[4][2];
#pragma unroll
  for (int i = 0; i < 4; i++)
#pragma unroll
    for (int j = 0; j < 2; j++) { acc1[i][j] = (f32x4){0,0,0,0}; acc3[i][j] = (f32x4){0,0,0,0}; }

  int wv = tid >> 6;
  int lane = tid & 63;
  int wr = (wv >> 1) * 64;
  int wc = (wv & 1) * 32;
  int lrow = lane & 15;
  int lk4 = lane >> 4;

  for (int k0 = 0; k0 < DD; k0 += 64) {
    if (k0) __syncthreads();
#pragma unroll
    for (int i = 0; i < 4; i++)
      GLL16(hb + asrc[i] + k0, Ab + i * 4096 + tid * 16);
#pragma unroll
    for (int i = 0; i < 4; i++) {
      GLL16(w1f + bsrc[i] + k0, B1 + i * 4096 + tid * 16);
      GLL16(w3f + bsrc[i] + k0, B3 + i * 4096 + tid * 16);
    }
    __syncthreads();
#pragma unroll
    for (int kk = 0; kk < 2; kk++) {
      int kseg = kk * 4 + lk4;
      int fs = kk * 8 + lk4 * 2;
      bf16x8 af[4], b1f[2], b3f[2];
#pragma unroll
      for (int i = 0; i < 4; i++) {
        int row = wr + i * 16 + lrow;
        af[i] = *(const bf16x8*)(Ab + row * 128 + ((kseg ^ (row & 7)) * 16));
      }
#pragma unroll
      for (int j = 0; j < 2; j++) {
        int row = wc + j * 16 + lrow;
        int rx = row & 15;
        float4 a0 = *(const float4*)(B1 + row * 256 + ((fs ^ rx) * 16));
        float4 a1 = *(const float4*)(B1 + row * 256 + (((fs + 1) ^ rx) * 16));
        b1f[j] = cvt8(a0, a1);
        float4 c0 = *(const float4*)(B3 + row * 256 + ((fs ^ rx) * 16));
        float4 c1 = *(const float4*)(B3 + row * 256 + (((fs + 1) ^ rx) * 16));
        b3f[j] = cvt8(c0, c1);
      }
#pragma unroll
      for (int i = 0; i < 4; i++)
#pragma unroll
        for (int j = 0; j < 2; j++) {
          acc1[i][j] = __builtin_amdgcn_mfma_f32_16x16x32_bf16(af[i], b1f[j], acc1[i][j], 0, 0, 0);
          acc3[i][j] = __builtin_amdgcn_mfma_f32_16x16x32_bf16(af[i], b3f[j], acc3[i][j], 0, 0, 0);
        }
    }
  }
  int crow0 = wr + (lane >> 4) * 4;
  int ccol0 = wc + (lane & 15);
#pragma unroll
  for (int i = 0; i < 4; i++)
#pragma unroll
    for (int j = 0; j < 2; j++)
#pragma unroll
      for (int r = 0; r < 4; r++) {
        int trow = crow0 + i * 16 + r;
        if (row0 + trow < cnt) {
          float g = acc1[i][j][r];
          float sg = g / (1.f + __expf(-g));
          float val = sg * acc3[i][j][r];
          gated[(size_t)(offe + row0 + trow) * FF + (fbase + ccol0 + j * 16)] = f2bf(val);
        }
      }
}

__global__ __launch_bounds__(256) void gemm2_kernel_fb(
    const float* __restrict__ w2f, const unsigned short* __restrict__ gated,
    const int* __restrict__ counts, const int* __restrict__ offsets,
    float* __restrict__ eout) {
  __shared__ __align__(16) char lds[49152];
  char* Ab = lds;
  char* Bb = lds + 16384;

  int bid = blockIdx.x;
  int x = bid & 7;
  int rest = bid >> 3;
  int m = rest & 31;
  int q = rest >> 5;
  int p = x + 8 * q;
  int n = p & 15;
  int e = p >> 4;
  int cnt = counts[e];
  int row0 = m * 128;
  if (row0 >= cnt) return;
  int offe = offsets[e];
  int tid = threadIdx.x;

  long asrc[4];
#pragma unroll
  for (int i = 0; i < 4; i++) {
    int r = i * 32 + (tid >> 3);
    int rr = row0 + r; if (rr >= cnt) rr = cnt - 1;
    asrc[i] = (long)(offe + rr) * FF + (((tid & 7) ^ (r & 7)) * 8);
  }
  int dbase = n * 128;
  long ebase = (long)e * DD * FF;
  long bsrc[8];
#pragma unroll
  for (int i = 0; i < 8; i++) {
    int r = i * 16 + (tid >> 4);
    bsrc[i] = ebase + (long)(dbase + r) * FF + (((tid & 15) ^ (r & 15)) * 4);
  }

  f32x4 acc[4][4];
#pragma unroll
  for (int i = 0; i < 4; i++)
#pragma unroll
    for (int j = 0; j < 4; j++) acc[i][j] = (f32x4){0,0,0,0};

  int wv = tid >> 6;
  int lane = tid & 63;
  int wr = (wv >> 1) * 64;
  int wc = (wv & 1) * 64;
  int lrow = lane & 15;
  int lk4 = lane >> 4;

  for (int k0 = 0; k0 < FF; k0 += 64) {
    if (k0) __syncthreads();
#pragma unroll
    for (int i = 0; i < 4; i++)
      GLL16(gated + asrc[i] + k0, Ab + i * 4096 + tid * 16);
#pragma unroll
    for (int i = 0; i < 8; i++)
      GLL16(w2f + bsrc[i] + k0, Bb + i * 4096 + tid * 16);
    __syncthreads();
#pragma unroll
    for (int kk = 0; kk < 2; kk++) {
      int kseg = kk * 4 + lk4;
      int fs = kk * 8 + lk4 * 2;
      bf16x8 af[4], bf[4];
#pragma unroll
      for (int i = 0; i < 4; i++) {
        int row = wr + i * 16 + lrow;
        af[i] = *(const bf16x8*)(Ab + row * 128 + ((kseg ^ (row & 7)) * 16));
      }
#pragma unroll
      for (int j = 0; j < 4; j++) {
        int row = wc + j * 16 + lrow;
        int rx = row & 15;
        float4 a0 = *(const float4*)(Bb + row * 256 + ((fs ^ rx) * 16));
        float4 a1 = *(const float4*)(Bb + row * 256 + (((fs + 1) ^ rx) * 16));
        bf[j] = cvt8(a0, a1);
      }
#pragma unroll
      for (int i = 0; i < 4; i++)
#pragma unroll
        for (int j = 0; j < 4; j++)
          acc[i][j] = __builtin_amdgcn_mfma_f32_16x16x32_bf16(af[i], bf[j], acc[i][j], 0, 0, 0);
    }
  }
  int crow0 = wr + (lane >> 4) * 4;
  int ccol0 = wc + (lane & 15);
#pragma unroll
  for (int i = 0; i < 4; i++)
#pragma unroll
    for (int j = 0; j < 4; j++)
#pragma unroll
      for (int r = 0; r < 4; r++) {
        int trow = crow0 + i * 16 + r;
        if (row0 + trow < cnt)
          eout[(size_t)(offe + row0 + trow) * DD + (dbase + ccol0 + j * 16)] = acc[i][j][r];
      }
}

// ---------------- gather: final = sum_k w_k * eout[slot_k] ----------------
__global__ void gather_kernel(const float* __restrict__ eout, const int* __restrict__ offsets,
                              const int* __restrict__ sel_e, const int* __restrict__ sel_slot,
                              const float* __restrict__ sel_w, float* __restrict__ out) {
  int idx = blockIdx.x * 256 + threadIdx.x;
  int t = idx >> 9;
  int c = idx & 511;
  int ea = sel_e[2 * t], eb = sel_e[2 * t + 1];
  int sa = offsets[ea] + sel_slot[2 * t];
  int sb = offsets[eb] + sel_slot[2 * t + 1];
  float wa = sel_w[2 * t], wb = sel_w[2 * t + 1];
  float4 va = ((const float4*)(eout + (size_t)sa * DD))[c];
  float4 vb = ((const float4*)(eout + (size_t)sb * DD))[c];
  float4 o;
  o.x = wa * va.x + wb * vb.x;
  o.y = wa * va.y + wb * vb.y;
  o.z = wa * va.z + wb * vb.z;
  o.w = wa * va.w + wb * vb.w;
  ((float4*)(out + (size_t)t * DD))[c] = o;
}

extern "C" void kernel_launch(void* const* d_in, const int* in_sizes, int n_in,
                              void* d_out, int out_size, void* d_ws, size_t ws_size,
                              hipStream_t stream) {
  const float* h  = (const float*)d_in[0];
  const float* gw = (const float*)d_in[1];
  const float* w1 = (const float*)d_in[2];
  const float* w2 = (const float*)d_in[3];
  const float* w3 = (const float*)d_in[4];
  float* out = (float*)d_out;
  float* logits = out + (size_t)TT * DD;

  char* wp = (char*)d_ws;
  int* counts = (int*)wp; wp += 256;
  int* offsets = (int*)wp; wp += 256;
  int* tok_idx = (int*)wp; wp += (size_t)NE * TT * 4;
  int* sel_e = (int*)wp; wp += (size_t)TT * 2 * 4;
  int* sel_slot = (int*)wp; wp += (size_t)TT * 2 * 4;
  float* sel_w = (float*)wp; wp += (size_t)TT * 2 * 4;
  unsigned short* hb = (unsigned short*)wp; wp += (size_t)TT * DD * 2;
  unsigned short* gated = (unsigned short*)wp; wp += (size_t)TT * TKK * FF * 2;
  float* eout = (float*)wp; wp += (size_t)TT * TKK * DD * 4;
  if ((size_t)(wp - (char*)d_ws) > ws_size) return;  // base scratch must fit

  long nw = (long)NE * FF * DD;
  unsigned short* w1b = (unsigned short*)wp; wp += (size_t)nw * 2;
  unsigned short* w3b = (unsigned short*)wp; wp += (size_t)nw * 2;
  unsigned short* w2b = (unsigned short*)wp; wp += (size_t)nw * 2;
  bool wb16 = ((size_t)(wp - (char*)d_ws) <= ws_size);

  hipMemsetAsync(counts, 0, 32, stream);
  if (wb16) {
    prep_kernel<<<NCB + TT / 4, 256, 0, stream>>>(
        h, gw, logits, hb, counts, tok_idx, sel_e, sel_slot, sel_w,
        w1, w1b, w3, w3b, w2, w2b);
    offsets_kernel<<<1, 64, 0, stream>>>(counts, offsets);
    gemm1_8p<<<8 * 16 * 32, 512, 0, stream>>>(w1b, w3b, hb, tok_idx, counts, offsets, gated);
    gemm2_8p<<<8 * 16 * 16, 512, 0, stream>>>(w2b, gated, counts, offsets, eout);
  } else {
    router_kernel<<<TT, 64, 0, stream>>>(h, gw, logits, hb, counts, tok_idx, sel_e, sel_slot, sel_w);
    offsets_kernel<<<1, 64, 0, stream>>>(counts, offsets);
    gemm1_kernel_fb<<<8 * 32 * 64, 256, 0, stream>>>(w1, w3, hb, tok_idx, counts, offsets, gated);
    gemm2_kernel_fb<<<8 * 32 * 16, 256, 0, stream>>>(w2, gated, counts, offsets, eout);
  }
  gather_kernel<<<(TT * DD / 4) / 256, 256, 0, stream>>>(eout, offsets, sel_e, sel_slot, sel_w, out);
}

// Round 8
// 846.221 us; speedup vs baseline: 1.0677x; 1.0180x over previous
//
#include <hip/hip_runtime.h>
#include <hip/hip_bf16.h>
#include <stdint.h>

#define NE 8
#define TKK 2
#define DD 2048
#define FF 4096
#define TT 4096      // tokens = 2*2048
#define NCB 49152    // one-shot convert blocks: 3 * nw / (256*16)

typedef __attribute__((ext_vector_type(8))) short bf16x8;
typedef __attribute__((ext_vector_type(4))) float f32x4;

__device__ inline unsigned short f2bf(float f) {
  union { float f; unsigned u; } x; x.f = f;
  unsigned r = x.u + 0x7fffu + ((x.u >> 16) & 1u);
  return (unsigned short)(r >> 16);
}

__device__ inline float bf2f(unsigned short v) {
  union { unsigned u; float f; } x; x.u = (unsigned)v << 16; return x.f;
}

__device__ inline bf16x8 cvt8(float4 a, float4 b) {
  union { unsigned short h[8]; bf16x8 v; } x;
  x.h[0] = f2bf(a.x); x.h[1] = f2bf(a.y); x.h[2] = f2bf(a.z); x.h[3] = f2bf(a.w);
  x.h[4] = f2bf(b.x); x.h[5] = f2bf(b.y); x.h[6] = f2bf(b.z); x.h[7] = f2bf(b.w);
  return x.v;
}

// one-shot 16-element convert: 4 independent loads first (ILP), then 2 stores
__device__ __forceinline__ void conv16(const float* __restrict__ src,
                                       unsigned short* __restrict__ dst, long i) {
  float4 a0 = *(const float4*)(src + i);
  float4 a1 = *(const float4*)(src + i + 4);
  float4 a2 = *(const float4*)(src + i + 8);
  float4 a3 = *(const float4*)(src + i + 12);
  union { unsigned short h[8]; uint4 v; } o0, o1;
  o0.h[0] = f2bf(a0.x); o0.h[1] = f2bf(a0.y); o0.h[2] = f2bf(a0.z); o0.h[3] = f2bf(a0.w);
  o0.h[4] = f2bf(a1.x); o0.h[5] = f2bf(a1.y); o0.h[6] = f2bf(a1.z); o0.h[7] = f2bf(a1.w);
  o1.h[0] = f2bf(a2.x); o1.h[1] = f2bf(a2.y); o1.h[2] = f2bf(a2.z); o1.h[3] = f2bf(a2.w);
  o1.h[4] = f2bf(a3.x); o1.h[5] = f2bf(a3.y); o1.h[6] = f2bf(a3.z); o1.h[7] = f2bf(a3.w);
  *(uint4*)(dst + i) = o0.v;
  *(uint4*)(dst + i + 8) = o1.v;
}

#define GLL16(g, l) __builtin_amdgcn_global_load_lds( \
    (__attribute__((address_space(1))) void*)(void*)(g), \
    (__attribute__((address_space(3))) void*)(l), 16, 0, 0)

#define LDV(p) (*(const bf16x8*)(p))
#define MF(d, a, b) d = __builtin_amdgcn_mfma_f32_16x16x32_bf16(a, b, d, 0, 0, 0)
#define WAITVN(n) asm volatile("s_waitcnt vmcnt(" #n ")" ::: "memory")
#define WAITL0() do { asm volatile("s_waitcnt lgkmcnt(0)" ::: "memory"); \
                      __builtin_amdgcn_sched_barrier(0); } while (0)
#define BAR() do { asm volatile("" ::: "memory"); __builtin_amdgcn_s_barrier(); \
                   asm volatile("" ::: "memory"); } while (0)

// ---------------- router body (one wave = one token) ----------------
__device__ __forceinline__ void router_one(
    int t, int lane, const float* __restrict__ h, const float* __restrict__ gw,
    float* __restrict__ logits, unsigned short* __restrict__ hb,
    int* __restrict__ counts, int* __restrict__ tok_idx,
    int* __restrict__ sel_e, int* __restrict__ sel_slot, float* __restrict__ sel_w) {
  const float4* hr = (const float4*)(h + (size_t)t * DD);
  float4 hv[8];
  float acc[NE];
#pragma unroll
  for (int e = 0; e < NE; e++) acc[e] = 0.f;
#pragma unroll
  for (int j = 0; j < 8; j++) hv[j] = hr[j * 64 + lane];
  ushort4* hbr = (ushort4*)(hb + (size_t)t * DD);
#pragma unroll
  for (int j = 0; j < 8; j++) {
    ushort4 o;
    o.x = f2bf(hv[j].x); o.y = f2bf(hv[j].y); o.z = f2bf(hv[j].z); o.w = f2bf(hv[j].w);
    hbr[j * 64 + lane] = o;
  }
#pragma unroll
  for (int e = 0; e < NE; e++) {
    const float4* g = (const float4*)(gw + (size_t)e * DD);
    float a = 0.f;
#pragma unroll
    for (int j = 0; j < 8; j++) {
      float4 gv = g[j * 64 + lane];
      a += hv[j].x * gv.x + hv[j].y * gv.y + hv[j].z * gv.z + hv[j].w * gv.w;
    }
    acc[e] = a;
  }
#pragma unroll
  for (int e = 0; e < NE; e++) {
    float v = acc[e];
#pragma unroll
    for (int o = 32; o > 0; o >>= 1) v += __shfl_xor(v, o, 64);
    acc[e] = v;
  }
  if (lane == 0) {
#pragma unroll
    for (int e = 0; e < NE; e++) logits[(size_t)t * NE + e] = acc[e];
    int e1 = 0; float m1 = acc[0];
#pragma unroll
    for (int e = 1; e < NE; e++) if (acc[e] > m1) { m1 = acc[e]; e1 = e; }
    int e2 = -1; float m2 = -3.4e38f;
#pragma unroll
    for (int e = 0; e < NE; e++) if (e != e1 && acc[e] > m2) { m2 = acc[e]; e2 = e; }
    float s = expf(m2 - m1);
    float wa = 1.f / (1.f + s);
    float wb = s * wa;
    int s1 = atomicAdd(&counts[e1], 1);
    tok_idx[e1 * TT + s1] = t;
    int s2 = atomicAdd(&counts[e2], 1);
    tok_idx[e2 * TT + s2] = t;
    sel_e[2 * t] = e1; sel_slot[2 * t] = s1; sel_w[2 * t] = wa;
    sel_e[2 * t + 1] = e2; sel_slot[2 * t + 1] = s2; sel_w[2 * t + 1] = wb;
  }
}

__global__ void router_kernel(const float* __restrict__ h, const float* __restrict__ gw,
                              float* __restrict__ logits, unsigned short* __restrict__ hb,
                              int* __restrict__ counts, int* __restrict__ tok_idx,
                              int* __restrict__ sel_e, int* __restrict__ sel_slot,
                              float* __restrict__ sel_w) {
  router_one(blockIdx.x, threadIdx.x, h, gw, logits, hb, counts, tok_idx, sel_e, sel_slot, sel_w);
}

// ---------------- prep: one-shot w1/w3/w2 convert + router, one dispatch ----------------
__global__ __launch_bounds__(256) void prep_kernel(
    const float* __restrict__ h, const float* __restrict__ gw,
    float* __restrict__ logits, unsigned short* __restrict__ hb,
    int* __restrict__ counts, int* __restrict__ tok_idx,
    int* __restrict__ sel_e, int* __restrict__ sel_slot, float* __restrict__ sel_w,
    const float* __restrict__ w1, unsigned short* __restrict__ w1b,
    const float* __restrict__ w3, unsigned short* __restrict__ w3b,
    const float* __restrict__ w2, unsigned short* __restrict__ w2b) {
  int b = blockIdx.x;
  if (b < NCB) {
    int t = b >> 14;                 // 16384 blocks per tensor
    long j = ((long)(b & 16383) * 256 + threadIdx.x) * 16;
    const float* src = (t == 0) ? w1 : (t == 1) ? w3 : w2;
    unsigned short* dst = (t == 0) ? w1b : (t == 1) ? w3b : w2b;
    conv16(src, dst, j);
    return;
  }
  int rb = b - NCB;
  router_one(rb * 4 + (threadIdx.x >> 6), threadIdx.x & 63,
             h, gw, logits, hb, counts, tok_idx, sel_e, sel_slot, sel_w);
}

__global__ void offsets_kernel(const int* __restrict__ counts, int* __restrict__ offsets) {
  if (threadIdx.x == 0) {
    int r = 0;
    for (int e = 0; e < NE; e++) { offsets[e] = r; r += counts[e]; }
  }
}

// =========================================================================
// m201-faithful phase template: reads issued BEFORE the gating barrier,
// lgkmcnt(0)+sched_barrier after; counted vmcnt only at validity phases.
// Phase map: ph0=(rows0-3,k0) ph1=(rows0-3,k1) ph2=(rows4-7,k0) ph3=(rows4-7,k1)
// -> ph1/ph3 reads have no validity gate (same chunks already drained).
// Issue FIFO per K-tile (gemm1): A0,A2 | B1x2 | B3x2 | A1,A3
//   ph0: vmcnt(2) leaves A1,A3 (rows4-7, needed only at ph2)
//   ph2: vmcnt(4) drains old A1,A3 (outstanding = oldA1,A3 + newA0,A2,B1x2)
// =========================================================================

// ---- gemm1_8p: gated = silu(X w1^T) * (X w3^T), dual-B, K=DD ----
// grid: 4096 = x(8) * m(16) * q(32); p = x+8q -> n = p&31, e = p>>5
__global__ __launch_bounds__(512, 2) void gemm1_8p(
    const unsigned short* __restrict__ w1b, const unsigned short* __restrict__ w3b,
    const unsigned short* __restrict__ hb, const int* __restrict__ tok_idx,
    const int* __restrict__ counts, const int* __restrict__ offsets,
    unsigned short* __restrict__ gated) {
  __shared__ __align__(16) char lds[131072];  // A[2][256][64] @0, B1[2][128][64] @65536, B3 @98304

  int bid = blockIdx.x;
  int x = bid & 7, rest = bid >> 3;
  int m = rest & 15, q = rest >> 4;
  int p = x + 8 * q;
  int n = p & 31, e = p >> 5;
  int cnt = counts[e];
  int row0 = m * 256;
  if (row0 >= cnt) return;
  int offe = offsets[e];
  int tid = threadIdx.x;
  int lane = tid & 63;
  int wv = tid >> 6;
  int wm = wv >> 2, wn = wv & 3;

  int swz = ((tid & 7) ^ ((tid >> 3) & 7)) * 8;
  long asrc[4];
#pragma unroll
  for (int i = 0; i < 4; i++) {
    int r = i * 64 + (tid >> 3);
    int rr = row0 + r; if (rr >= cnt) rr = cnt - 1;
    int tok = tok_idx[e * TT + rr];
    asrc[i] = (long)tok * DD + swz;
  }
  int fbase = n * 128;
  long ebw = (long)e * FF * DD;
  long bs[2];
#pragma unroll
  for (int i = 0; i < 2; i++) {
    int r = i * 64 + (tid >> 3);
    bs[i] = ebw + (long)(fbase + r) * DD + swz;
  }

#define G1A(c, i, ko)  GLL16(hb  + asrc[i] + (ko), lds +           (c) * 32768 + (i) * 8192 + tid * 16)
#define G1B1(c, i, ko) GLL16(w1b + bs[i]   + (ko), lds + 65536 +  (c) * 16384 + (i) * 8192 + tid * 16)
#define G1B3(c, i, ko) GLL16(w3b + bs[i]   + (ko), lds + 98304 +  (c) * 16384 + (i) * 8192 + tid * 16)

  int arow[8], brow[2];
#pragma unroll
  for (int i = 0; i < 8; i++) arow[i] = (wm * 128 + i * 16 + (lane & 15)) * 128;
#pragma unroll
  for (int j = 0; j < 2; j++) brow[j] = (wn * 32 + j * 16 + (lane & 15)) * 128;
  int kx0 = (((lane >> 4)) ^ (lane & 7)) * 16;
  int kx1 = ((4 + (lane >> 4)) ^ (lane & 7)) * 16;

  f32x4 acc1[8][2], acc3[8][2];
#pragma unroll
  for (int i = 0; i < 8; i++)
#pragma unroll
    for (int j = 0; j < 2; j++) { acc1[i][j] = (f32x4){0,0,0,0}; acc3[i][j] = (f32x4){0,0,0,0}; }

  // prologue: tile 0 into buf 0, FIFO order
  G1A(0, 0, 0); G1A(0, 2, 0);
  G1B1(0, 0, 0); G1B1(0, 1, 0);
  G1B3(0, 0, 0); G1B3(0, 1, 0);
  G1A(0, 1, 0); G1A(0, 3, 0);

  int cur = 0;
  for (int kt = 0; kt < DD / 64; kt++) {
    int ko = (kt + 1) * 64;
    bool st = (kt < DD / 64 - 1);
    int nc = cur ^ 1;
    const char* Ac  = lds + cur * 32768;
    const char* B1c = lds + 65536 + cur * 16384;
    const char* B3c = lds + 98304 + cur * 16384;
    bf16x8 a[4];

    // ---- ph0: rows0-3, k0 ----
    WAITVN(2);
    BAR();
    bf16x8 b10k0 = LDV(B1c + brow[0] + kx0), b11k0 = LDV(B1c + brow[1] + kx0);
    bf16x8 b30k0 = LDV(B3c + brow[0] + kx0), b31k0 = LDV(B3c + brow[1] + kx0);
#pragma unroll
    for (int i = 0; i < 4; i++) a[i] = LDV(Ac + arow[i] + kx0);
    if (st) { G1A(nc, 0, ko); G1A(nc, 2, ko); }
    WAITL0();
    __builtin_amdgcn_s_setprio(1);
#pragma unroll
    for (int i = 0; i < 4; i++) {
      MF(acc1[i][0], a[i], b10k0); MF(acc1[i][1], a[i], b11k0);
      MF(acc3[i][0], a[i], b30k0); MF(acc3[i][1], a[i], b31k0);
    }
    __builtin_amdgcn_s_setprio(0);
    BAR();

    // ---- ph1: rows0-3, k1 (no validity gate; reads overlap) ----
    bf16x8 b10k1 = LDV(B1c + brow[0] + kx1), b11k1 = LDV(B1c + brow[1] + kx1);
    bf16x8 b30k1 = LDV(B3c + brow[0] + kx1), b31k1 = LDV(B3c + brow[1] + kx1);
#pragma unroll
    for (int i = 0; i < 4; i++) a[i] = LDV(Ac + arow[i] + kx1);
    if (st) { G1B1(nc, 0, ko); G1B1(nc, 1, ko); }
    WAITL0();
    __builtin_amdgcn_s_setprio(1);
#pragma unroll
    for (int i = 0; i < 4; i++) {
      MF(acc1[i][0], a[i], b10k1); MF(acc1[i][1], a[i], b11k1);
      MF(acc3[i][0], a[i], b30k1); MF(acc3[i][1], a[i], b31k1);
    }
    __builtin_amdgcn_s_setprio(0);

    // ---- ph2: rows4-7, k0 (gate on old A1,A3) ----
    if (st) WAITVN(4); else WAITVN(0);
    BAR();
#pragma unroll
    for (int i = 0; i < 4; i++) a[i] = LDV(Ac + arow[4 + i] + kx0);
    if (st) { G1B3(nc, 0, ko); G1B3(nc, 1, ko); }
    WAITL0();
    __builtin_amdgcn_s_setprio(1);
#pragma unroll
    for (int i = 0; i < 4; i++) {
      MF(acc1[4 + i][0], a[i], b10k0); MF(acc1[4 + i][1], a[i], b11k0);
      MF(acc3[4 + i][0], a[i], b30k0); MF(acc3[4 + i][1], a[i], b31k0);
    }
    __builtin_amdgcn_s_setprio(0);
    BAR();

    // ---- ph3: rows4-7, k1 ----
#pragma unroll
    for (int i = 0; i < 4; i++) a[i] = LDV(Ac + arow[4 + i] + kx1);
    if (st) { G1A(nc, 1, ko); G1A(nc, 3, ko); }
    WAITL0();
    __builtin_amdgcn_s_setprio(1);
#pragma unroll
    for (int i = 0; i < 4; i++) {
      MF(acc1[4 + i][0], a[i], b10k1); MF(acc1[4 + i][1], a[i], b11k1);
      MF(acc3[4 + i][0], a[i], b30k1); MF(acc3[4 + i][1], a[i], b31k1);
    }
    __builtin_amdgcn_s_setprio(0);
    cur = nc;
  }

  // epilogue: silu(c1)*c3 -> bf16
  int r0 = wm * 128 + ((lane >> 4) << 2);
  int c0 = fbase + wn * 32 + (lane & 15);
#pragma unroll
  for (int i = 0; i < 8; i++)
#pragma unroll
    for (int j = 0; j < 2; j++)
#pragma unroll
      for (int r = 0; r < 4; r++) {
        int tr = r0 + i * 16 + r;
        if (row0 + tr < cnt) {
          float g = acc1[i][j][r];
          float sg = g / (1.f + __expf(-g));
          gated[(size_t)(offe + row0 + tr) * FF + (c0 + j * 16)] = f2bf(sg * acc3[i][j][r]);
        }
      }
}

// ---- gemm2_8p: eout(bf16) = gated w2^T, single-B, K=FF, 2 phases/tile ----
// grid: 2048 = x(8) * m(16) * q(16); p = x+8q -> n = p&15, e = p>>4
// FIFO per tile: A0,A2 | B0,B1 | A1,A3 ; ph0 vmcnt(2), ph1 vmcnt(4)
__global__ __launch_bounds__(512, 2) void gemm2_8p(
    const unsigned short* __restrict__ w2b, const unsigned short* __restrict__ gated,
    const int* __restrict__ counts, const int* __restrict__ offsets,
    unsigned short* __restrict__ eout) {
  __shared__ __align__(16) char lds[98304];  // A[2][256][64] @0, B[2][128][64] @65536

  int bid = blockIdx.x;
  int x = bid & 7, rest = bid >> 3;
  int m = rest & 15, q = rest >> 4;
  int p = x + 8 * q;
  int n = p & 15, e = p >> 4;
  int cnt = counts[e];
  int row0 = m * 256;
  if (row0 >= cnt) return;
  int offe = offsets[e];
  int tid = threadIdx.x;
  int lane = tid & 63;
  int wv = tid >> 6;
  int wm = wv >> 2, wn = wv & 3;

  int swz = ((tid & 7) ^ ((tid >> 3) & 7)) * 8;
  long asrc[4];
#pragma unroll
  for (int i = 0; i < 4; i++) {
    int r = i * 64 + (tid >> 3);
    int rr = row0 + r; if (rr >= cnt) rr = cnt - 1;
    asrc[i] = (long)(offe + rr) * FF + swz;
  }
  int dbase = n * 128;
  long ebw = (long)e * DD * FF;
  long bs[2];
#pragma unroll
  for (int i = 0; i < 2; i++) {
    int r = i * 64 + (tid >> 3);
    bs[i] = ebw + (long)(dbase + r) * FF + swz;
  }

#define G2A(c, i, ko) GLL16(gated + asrc[i] + (ko), lds +          (c) * 32768 + (i) * 8192 + tid * 16)
#define G2B(c, i, ko) GLL16(w2b   + bs[i]   + (ko), lds + 65536 + (c) * 16384 + (i) * 8192 + tid * 16)

  int arow[8], brow[2];
#pragma unroll
  for (int i = 0; i < 8; i++) arow[i] = (wm * 128 + i * 16 + (lane & 15)) * 128;
#pragma unroll
  for (int j = 0; j < 2; j++) brow[j] = (wn * 32 + j * 16 + (lane & 15)) * 128;
  int kx0 = (((lane >> 4)) ^ (lane & 7)) * 16;
  int kx1 = ((4 + (lane >> 4)) ^ (lane & 7)) * 16;

  f32x4 acc[8][2];
#pragma unroll
  for (int i = 0; i < 8; i++)
#pragma unroll
    for (int j = 0; j < 2; j++) acc[i][j] = (f32x4){0,0,0,0};

  // prologue: tile 0 into buf 0, FIFO order
  G2A(0, 0, 0); G2A(0, 2, 0);
  G2B(0, 0, 0); G2B(0, 1, 0);
  G2A(0, 1, 0); G2A(0, 3, 0);

  int cur = 0;
  for (int kt = 0; kt < FF / 64; kt++) {
    int ko = (kt + 1) * 64;
    bool st = (kt < FF / 64 - 1);
    int nc = cur ^ 1;
    const char* Ac = lds + cur * 32768;
    const char* Bc = lds + 65536 + cur * 16384;
    bf16x8 a0[4], a1v[4];

    // ---- ph0: rows0-3, both k-halves ----
    WAITVN(2);
    BAR();
    bf16x8 b0 = LDV(Bc + brow[0] + kx0), b1 = LDV(Bc + brow[1] + kx0);
    bf16x8 b2 = LDV(Bc + brow[0] + kx1), b3 = LDV(Bc + brow[1] + kx1);
#pragma unroll
    for (int i = 0; i < 4; i++) { a0[i] = LDV(Ac + arow[i] + kx0); a1v[i] = LDV(Ac + arow[i] + kx1); }
    if (st) { G2A(nc, 0, ko); G2A(nc, 2, ko); G2B(nc, 0, ko); G2B(nc, 1, ko); }
    WAITL0();
    __builtin_amdgcn_s_setprio(1);
#pragma unroll
    for (int i = 0; i < 4; i++) {
      MF(acc[i][0], a0[i], b0); MF(acc[i][1], a0[i], b1);
      MF(acc[i][0], a1v[i], b2); MF(acc[i][1], a1v[i], b3);
    }
    __builtin_amdgcn_s_setprio(0);

    // ---- ph1: rows4-7, both k-halves (gate on old A1,A3) ----
    if (st) WAITVN(4); else WAITVN(0);
    BAR();
#pragma unroll
    for (int i = 0; i < 4; i++) { a0[i] = LDV(Ac + arow[4 + i] + kx0); a1v[i] = LDV(Ac + arow[4 + i] + kx1); }
    if (st) { G2A(nc, 1, ko); G2A(nc, 3, ko); }
    WAITL0();
    __builtin_amdgcn_s_setprio(1);
#pragma unroll
    for (int i = 0; i < 4; i++) {
      MF(acc[4 + i][0], a0[i], b0); MF(acc[4 + i][1], a0[i], b1);
      MF(acc[4 + i][0], a1v[i], b2); MF(acc[4 + i][1], a1v[i], b3);
    }
    __builtin_amdgcn_s_setprio(0);
    cur = nc;
  }

  int r0 = wm * 128 + ((lane >> 4) << 2);
  int c0 = dbase + wn * 32 + (lane & 15);
#pragma unroll
  for (int i = 0; i < 8; i++)
#pragma unroll
    for (int j = 0; j < 2; j++)
#pragma unroll
      for (int r = 0; r < 4; r++) {
        int tr = r0 + i * 16 + r;
        if (row0 + tr < cnt)
          eout[(size_t)(offe + row0 + tr) * DD + (c0 + j * 16)] = f2bf(acc[i][j][r]);
      }
}

// ---------------- fallback kernels (ws too small) ----------------
__global__ __launch_bounds__(256) void gemm1_kernel_fb(
    const float* __restrict__ w1f, const float* __restrict__ w3f,
    const unsigned short* __restrict__ hb, const int* __restrict__ tok_idx,
    const int* __restrict__ counts, const int* __restrict__ offsets,
    unsigned short* __restrict__ gated) {
  __shared__ __align__(16) char lds[49152];
  char* Ab = lds;
  char* B1 = lds + 16384;
  char* B3 = lds + 32768;

  int bid = blockIdx.x;
  int x = bid & 7;
  int rest = bid >> 3;
  int m = rest & 31;
  int q = rest >> 5;
  int p = x + 8 * q;
  int n = p & 63;
  int e = p >> 6;
  int cnt = counts[e];
  int row0 = m * 128;
  if (row0 >= cnt) return;
  int offe = offsets[e];
  int tid = threadIdx.x;

  long asrc[4];
#pragma unroll
  for (int i = 0; i < 4; i++) {
    int r = i * 32 + (tid >> 3);
    int rr = row0 + r; if (rr >= cnt) rr = cnt - 1;
    int tok = tok_idx[e * TT + rr];
    asrc[i] = (long)tok * DD + (((tid & 7) ^ (r & 7)) * 8);
  }
  int fbase = n * 64;
  long ebase = (long)e * FF * DD;
  long bsrc[4];
#pragma unroll
  for (int i = 0; i < 4; i++) {
    int r = i * 16 + (tid >> 4);
    bsrc[i] = ebase + (long)(fbase + r) * DD + (((tid & 15) ^ (r & 15)) * 4);
  }

  f32x4 acc1[4][2], acc3[4][2];
#pragma unroll
  for (int i = 0; i < 4; i++)
#pragma unroll
    for (int j = 0; j < 2; j++) { acc1[i][j] = (f32x4){0,0,0,0}; acc3[i][j] = (f32x4){0,0,0,0}; }

  int wv = tid >> 6;
  int lane = tid & 63;
  int wr = (wv >> 1) * 64;
  int wc = (wv & 1) * 32;
  int lrow = lane & 15;
  int lk4 = lane >> 4;

  for (int k0 = 0; k0 < DD; k0 += 64) {
    if (k0) __syncthreads();
#pragma unroll
    for (int i = 0; i < 4; i++)
      GLL16(hb + asrc[i] + k0, Ab + i * 4096 + tid * 16);
#pragma unroll
    for (int i = 0; i < 4; i++) {
      GLL16(w1f + bsrc[i] + k0, B1 + i * 4096 + tid * 16);
      GLL16(w3f + bsrc[i] + k0, B3 + i * 4096 + tid * 16);
    }
    __syncthreads();
#pragma unroll
    for (int kk = 0; kk < 2; kk++) {
      int kseg = kk * 4 + lk4;
      int fs = kk * 8 + lk4 * 2;
      bf16x8 af[4], b1f[2], b3f[2];
#pragma unroll
      for (int i = 0; i < 4; i++) {
        int row = wr + i * 16 + lrow;
        af[i] = *(const bf16x8*)(Ab + row * 128 + ((kseg ^ (row & 7)) * 16));
      }
#pragma unroll
      for (int j = 0; j < 2; j++) {
        int row = wc + j * 16 + lrow;
        int rx = row & 15;
        float4 a0 = *(const float4*)(B1 + row * 256 + ((fs ^ rx) * 16));
        float4 a1 = *(const float4*)(B1 + row * 256 + (((fs + 1) ^ rx) * 16));
        b1f[j] = cvt8(a0, a1);
        float4 c0 = *(const float4*)(B3 + row * 256 + ((fs ^ rx) * 16));
        float4 c1 = *(const float4*)(B3 + row * 256 + (((fs + 1) ^ rx) * 16));
        b3f[j] = cvt8(c0, c1);
      }
#pragma unroll
      for (int i = 0; i < 4; i++)
#pragma unroll
        for (int j = 0; j < 2; j++) {
          acc1[i][j] = __builtin_amdgcn_mfma_f32_16x16x32_bf16(af[i], b1f[j], acc1[i][j], 0, 0, 0);
          acc3[i][j] = __builtin_amdgcn_mfma_f32_16x16x32_bf16(af[i], b3f[j], acc3[i][j], 0, 0, 0);
        }
    }
  }
  int crow0 = wr + (lane >> 4) * 4;
  int ccol0 = wc + (lane & 15);
#pragma unroll
  for (int i = 0; i < 4; i++)
#pragma unroll
    for (int j = 0; j < 2; j++)
#pragma unroll
      for (int r = 0; r < 4; r++) {
        int trow = crow0 + i * 16 + r;
        if (row0 + trow < cnt) {
          float g = acc1[i][j][r];
          float sg = g / (1.f + __expf(-g));
          float val = sg * acc3[i][j][r];
          gated[(size_t)(offe + row0 + trow) * FF + (fbase + ccol0 + j * 16)] = f2bf(val);
        }
      }
}

__global__ __launch_bounds__(256) void gemm2_kernel_fb(
    const float* __restrict__ w2f, const unsigned short* __restrict__ gated,
    const int* __restrict__ counts, const int* __restrict__ offsets,
    unsigned short* __restrict__ eout) {
  __shared__ __align__(16) char lds[49152];
  char* Ab = lds;
  char* Bb = lds + 16384;

  int bid = blockIdx.x;
  int x = bid & 7;
  int rest = bid >> 3;
  int m = rest & 31;
  int q = rest >> 5;
  int p = x + 8 * q;
  int n = p & 15;
  int e = p >> 4;
  int cnt = counts[e];
  int row0 = m * 128;
  if (row0 >= cnt) return;
  int offe = offsets[e];
  int tid = threadIdx.x;

  long asrc[4];
#pragma unroll
  for (int i = 0; i < 4; i++) {
    int r = i * 32 + (tid >> 3);
    int rr = row0 + r; if (rr >= cnt) rr = cnt - 1;
    asrc[i] = (long)(offe + rr) * FF + (((tid & 7) ^ (r & 7)) * 8);
  }
  int dbase = n * 128;
  long ebase = (long)e * DD * FF;
  long bsrc[8];
#pragma unroll
  for (int i = 0; i < 8; i++) {
    int r = i * 16 + (tid >> 4);
    bsrc[i] = ebase + (long)(dbase + r) * FF + (((tid & 15) ^ (r & 15)) * 4);
  }

  f32x4 acc[4][4];
#pragma unroll
  for (int i = 0; i < 4; i++)
#pragma unroll
    for (int j = 0; j < 4; j++) acc[i][j] = (f32x4){0,0,0,0};

  int wv = tid >> 6;
  int lane = tid & 63;
  int wr = (wv >> 1) * 64;
  int wc = (wv & 1) * 64;
  int lrow = lane & 15;
  int lk4 = lane >> 4;

  for (int k0 = 0; k0 < FF; k0 += 64) {
    if (k0) __syncthreads();
#pragma unroll
    for (int i = 0; i < 4; i++)
      GLL16(gated + asrc[i] + k0, Ab + i * 4096 + tid * 16);
#pragma unroll
    for (int i = 0; i < 8; i++)
      GLL16(w2f + bsrc[i] + k0, Bb + i * 4096 + tid * 16);
    __syncthreads();
#pragma unroll
    for (int kk = 0; kk < 2; kk++) {
      int kseg = kk * 4 + lk4;
      int fs = kk * 8 + lk4 * 2;
      bf16x8 af[4], bf[4];
#pragma unroll
      for (int i = 0; i < 4; i++) {
        int row = wr + i * 16 + lrow;
        af[i] = *(const bf16x8*)(Ab + row * 128 + ((kseg ^ (row & 7)) * 16));
      }
#pragma unroll
      for (int j = 0; j < 4; j++) {
        int row = wc + j * 16 + lrow;
        int rx = row & 15;
        float4 a0 = *(const float4*)(Bb + row * 256 + ((fs ^ rx) * 16));
        float4 a1 = *(const float4*)(Bb + row * 256 + (((fs + 1) ^ rx) * 16));
        bf[j] = cvt8(a0, a1);
      }
#pragma unroll
      for (int i = 0; i < 4; i++)
#pragma unroll
        for (int j = 0; j < 4; j++)
          acc[i][j] = __builtin_amdgcn_mfma_f32_16x16x32_bf16(af[i], bf[j], acc[i][j], 0, 0, 0);
    }
  }
  int crow0 = wr + (lane >> 4) * 4;
  int ccol0 = wc + (lane & 15);
#pragma unroll
  for (int i = 0; i < 4; i++)
#pragma unroll
    for (int j = 0; j < 4; j++)
#pragma unroll
      for (int r = 0; r < 4; r++) {
        int trow = crow0 + i * 16 + r;
        if (row0 + trow < cnt)
          eout[(size_t)(offe + row0 + trow) * DD + (dbase + ccol0 + j * 16)] = f2bf(acc[i][j][r]);
      }
}

// ---------------- gather: final = sum_k w_k * eout[slot_k] (bf16 eout) ----------------
__global__ void gather_kernel(const unsigned short* __restrict__ eout, const int* __restrict__ offsets,
                              const int* __restrict__ sel_e, const int* __restrict__ sel_slot,
                              const float* __restrict__ sel_w, float* __restrict__ out) {
  int idx = blockIdx.x * 256 + threadIdx.x;
  int t = idx >> 8;            // 256 chunks of 8 per row
  int c = (idx & 255) * 8;
  int ea = sel_e[2 * t], eb = sel_e[2 * t + 1];
  long sa = (long)(offsets[ea] + sel_slot[2 * t]) * DD + c;
  long sb = (long)(offsets[eb] + sel_slot[2 * t + 1]) * DD + c;
  float wa = sel_w[2 * t], wb = sel_w[2 * t + 1];
  union { uint4 v; unsigned short h[8]; } va, vb;
  va.v = *(const uint4*)(eout + sa);
  vb.v = *(const uint4*)(eout + sb);
  float4 o0, o1;
  o0.x = wa * bf2f(va.h[0]) + wb * bf2f(vb.h[0]);
  o0.y = wa * bf2f(va.h[1]) + wb * bf2f(vb.h[1]);
  o0.z = wa * bf2f(va.h[2]) + wb * bf2f(vb.h[2]);
  o0.w = wa * bf2f(va.h[3]) + wb * bf2f(vb.h[3]);
  o1.x = wa * bf2f(va.h[4]) + wb * bf2f(vb.h[4]);
  o1.y = wa * bf2f(va.h[5]) + wb * bf2f(vb.h[5]);
  o1.z = wa * bf2f(va.h[6]) + wb * bf2f(vb.h[6]);
  o1.w = wa * bf2f(va.h[7]) + wb * bf2f(vb.h[7]);
  float* op = out + (size_t)t * DD + c;
  *(float4*)op = o0;
  *(float4*)(op + 4) = o1;
}

extern "C" void kernel_launch(void* const* d_in, const int* in_sizes, int n_in,
                              void* d_out, int out_size, void* d_ws, size_t ws_size,
                              hipStream_t stream) {
  const float* h  = (const float*)d_in[0];
  const float* gw = (const float*)d_in[1];
  const float* w1 = (const float*)d_in[2];
  const float* w2 = (const float*)d_in[3];
  const float* w3 = (const float*)d_in[4];
  float* out = (float*)d_out;
  float* logits = out + (size_t)TT * DD;

  char* wp = (char*)d_ws;
  int* counts = (int*)wp; wp += 256;
  int* offsets = (int*)wp; wp += 256;
  int* tok_idx = (int*)wp; wp += (size_t)NE * TT * 4;
  int* sel_e = (int*)wp; wp += (size_t)TT * 2 * 4;
  int* sel_slot = (int*)wp; wp += (size_t)TT * 2 * 4;
  float* sel_w = (float*)wp; wp += (size_t)TT * 2 * 4;
  unsigned short* hb = (unsigned short*)wp; wp += (size_t)TT * DD * 2;
  unsigned short* gated = (unsigned short*)wp; wp += (size_t)TT * TKK * FF * 2;
  unsigned short* eout = (unsigned short*)wp; wp += (size_t)TT * TKK * DD * 2;
  if ((size_t)(wp - (char*)d_ws) > ws_size) return;  // base scratch must fit

  long nw = (long)NE * FF * DD;
  unsigned short* w1b = (unsigned short*)wp; wp += (size_t)nw * 2;
  unsigned short* w3b = (unsigned short*)wp; wp += (size_t)nw * 2;
  unsigned short* w2b = (unsigned short*)wp; wp += (size_t)nw * 2;
  bool wb16 = ((size_t)(wp - (char*)d_ws) <= ws_size);

  hipMemsetAsync(counts, 0, 32, stream);
  if (wb16) {
    prep_kernel<<<NCB + TT / 4, 256, 0, stream>>>(
        h, gw, logits, hb, counts, tok_idx, sel_e, sel_slot, sel_w,
        w1, w1b, w3, w3b, w2, w2b);
    offsets_kernel<<<1, 64, 0, stream>>>(counts, offsets);
    gemm1_8p<<<8 * 16 * 32, 512, 0, stream>>>(w1b, w3b, hb, tok_idx, counts, offsets, gated);
    gemm2_8p<<<8 * 16 * 16, 512, 0, stream>>>(w2b, gated, counts, offsets, eout);
  } else {
    router_kernel<<<TT, 64, 0, stream>>>(h, gw, logits, hb, counts, tok_idx, sel_e, sel_slot, sel_w);
    offsets_kernel<<<1, 64, 0, stream>>>(counts, offsets);
    gemm1_kernel_fb<<<8 * 32 * 64, 256, 0, stream>>>(w1, w3, hb, tok_idx, counts, offsets, gated);
    gemm2_kernel_fb<<<8 * 32 * 16, 256, 0, stream>>>(w2, gated, counts, offsets, eout);
  }
  gather_kernel<<<TT * DD / 8 / 256, 256, 0, stream>>>(eout, offsets, sel_e, sel_slot, sel_w, out);
}